// Round 1
// baseline (1570.336 us; speedup 1.0000x reference)
//
#include <hip/hip_runtime.h>

typedef unsigned short u16;
typedef __attribute__((ext_vector_type(8))) short short8;   // 8 x bf16 frag (4 VGPRs)
typedef __attribute__((ext_vector_type(4))) float floatx4;  // MFMA accumulator

#define MFMA16(a, b, c) __builtin_amdgcn_mfma_f32_16x16x32_bf16(a, b, c, 0, 0, 0)

// Problem constants
#define BB 16
#define KK 1024
#define NH 1024
#define HD 8
#define DK 128
#define MM (BB * KK)          // 16384 rows of flattened activations
#define ATT_OFF 16777216      // atted elems (16*1024*1024) before att in d_out

__device__ __forceinline__ u16 f2bf(float x) {  // RNE f32 -> bf16
  unsigned u = __builtin_bit_cast(unsigned, x);
  u += 0x7fffu + ((u >> 16) & 1u);
  return (u16)(u >> 16);
}

// ---------------- weight transpose+cast: in f32 [1024][1024] -> out bf16 [n][k] ----
__global__ __launch_bounds__(256) void tr_w(const float* __restrict__ in,
                                            u16* __restrict__ out) {
  __shared__ u16 t[32][36];
  const int tid = threadIdx.x;
  const int bx = blockIdx.x * 32;  // n base
  const int by = blockIdx.y * 32;  // k base
  const int r = tid >> 3, c4 = (tid & 7) * 4;
  float4 f = *(const float4*)(in + (size_t)(by + r) * 1024 + bx + c4);
  t[r][c4 + 0] = f2bf(f.x);
  t[r][c4 + 1] = f2bf(f.y);
  t[r][c4 + 2] = f2bf(f.z);
  t[r][c4 + 3] = f2bf(f.w);
  __syncthreads();
  union { u16 u[4]; uint2 v; } p;
#pragma unroll
  for (int i = 0; i < 4; i++) p.u[i] = t[c4 + i][r];
  *(uint2*)(out + (size_t)(bx + r) * 1024 + by + c4) = p.v;  // out[n][k] = in[k][n]
}

// ---------------- vv head transpose: vvb bf16 [b,i,h*128+d] -> vvT [bh][d][i] -------
__global__ __launch_bounds__(256) void tr_head(const u16* __restrict__ vvb,
                                               u16* __restrict__ vvT) {
  __shared__ u16 t[32][36];
  const int tid = threadIdx.x;
  const int bh = blockIdx.z, b = bh >> 3, h = bh & 7;
  const int i0 = blockIdx.x * 32, d0 = blockIdx.y * 32;
  const int r = tid >> 3, c4 = (tid & 7) * 4;
  union { u16 u[4]; uint2 v; } p;
  p.v = *(const uint2*)(vvb + (size_t)(b * KK + i0 + r) * NH + h * DK + d0 + c4);
  t[r][c4 + 0] = p.u[0];
  t[r][c4 + 1] = p.u[1];
  t[r][c4 + 2] = p.u[2];
  t[r][c4 + 3] = p.u[3];
  __syncthreads();
#pragma unroll
  for (int i = 0; i < 4; i++) p.u[i] = t[c4 + i][r];
  *(uint2*)(vvT + (size_t)(bh * DK + d0 + r) * KK + i0 + c4) = p.v;
}

// ---------------- generic MFMA GEMM: C = A[M,Kd] * Bt[N,Kd]^T (+bias) ---------------
// A is f32 (cast during staging) or bf16. Bt rows are k-contiguous bf16.
// Tile 128x128x32, 4 waves in 2x2, each wave 64x64 via 4x4 16x16x32 MFMA tiles.
template <bool A_BF16>
__global__ __launch_bounds__(256, 2) void gemm_bt(
    const void* __restrict__ Av, const u16* __restrict__ Bt,
    const float* __restrict__ bias, u16* __restrict__ Cb, float* __restrict__ Cf,
    int Kd, int ldc, long long aBatch, long long btBatch,
    long long cBatchB, long long cBatchH) {
  __shared__ __align__(16) u16 As[128 * 40];
  __shared__ __align__(16) u16 Bs[128 * 40];
  const int tid = threadIdx.x;
  const int z = blockIdx.z;
  const int nBase = blockIdx.x * 128;
  const int mBase = blockIdx.y * 128;
  const float* Af = (const float*)Av + (size_t)z * aBatch;
  const u16* Ah = (const u16*)Av + (size_t)z * aBatch;
  const u16* Bb = Bt + (size_t)z * btBatch;
  const size_t cOff = (size_t)(z >> 3) * cBatchB + (size_t)(z & 7) * cBatchH;

  const int wid = tid >> 6, lane = tid & 63;
  const int wm = (wid & 1) * 64, wn = (wid >> 1) * 64;
  const int lm = lane & 15, lq = lane >> 4;
  const int sRow = tid >> 1;          // staging: 2 threads per row
  const int sCol = (tid & 1) * 16;    // 16 k-elems each

  floatx4 acc[4][4] = {};

  for (int k0 = 0; k0 < Kd; k0 += 32) {
    union { u16 u[8]; uint4 v; } pa0, pa1;
    if (A_BF16) {
      const u16* ap = Ah + (size_t)(mBase + sRow) * Kd + k0 + sCol;
      pa0.v = *(const uint4*)ap;
      pa1.v = *(const uint4*)(ap + 8);
    } else {
      const float* ap = Af + (size_t)(mBase + sRow) * Kd + k0 + sCol;
      float4 f0 = *(const float4*)(ap + 0);
      float4 f1 = *(const float4*)(ap + 4);
      float4 f2 = *(const float4*)(ap + 8);
      float4 f3 = *(const float4*)(ap + 12);
      pa0.u[0] = f2bf(f0.x); pa0.u[1] = f2bf(f0.y);
      pa0.u[2] = f2bf(f0.z); pa0.u[3] = f2bf(f0.w);
      pa0.u[4] = f2bf(f1.x); pa0.u[5] = f2bf(f1.y);
      pa0.u[6] = f2bf(f1.z); pa0.u[7] = f2bf(f1.w);
      pa1.u[0] = f2bf(f2.x); pa1.u[1] = f2bf(f2.y);
      pa1.u[2] = f2bf(f2.z); pa1.u[3] = f2bf(f2.w);
      pa1.u[4] = f2bf(f3.x); pa1.u[5] = f2bf(f3.y);
      pa1.u[6] = f2bf(f3.z); pa1.u[7] = f2bf(f3.w);
    }
    const u16* bp = Bb + (size_t)(nBase + sRow) * Kd + k0 + sCol;
    uint4 pb0 = *(const uint4*)bp;
    uint4 pb1 = *(const uint4*)(bp + 8);

    *(uint4*)&As[sRow * 40 + sCol + 0] = pa0.v;
    *(uint4*)&As[sRow * 40 + sCol + 8] = pa1.v;
    *(uint4*)&Bs[sRow * 40 + sCol + 0] = pb0;
    *(uint4*)&Bs[sRow * 40 + sCol + 8] = pb1;
    __syncthreads();

    short8 af[4], bfr[4];
#pragma unroll
    for (int t = 0; t < 4; t++) {
      af[t]  = *(const short8*)&As[(wm + t * 16 + lm) * 40 + lq * 8];
      bfr[t] = *(const short8*)&Bs[(wn + t * 16 + lm) * 40 + lq * 8];
    }
#pragma unroll
    for (int i = 0; i < 4; i++)
#pragma unroll
      for (int j = 0; j < 4; j++)
        acc[i][j] = MFMA16(af[i], bfr[j], acc[i][j]);
    __syncthreads();
  }

  // epilogue: C/D layout col=lane&15, row=(lane>>4)*4+reg
#pragma unroll
  for (int i = 0; i < 4; i++) {
    const int rowL = wm + i * 16 + lq * 4;
#pragma unroll
    for (int j = 0; j < 4; j++) {
      const int col = nBase + wn + j * 16 + lm;
      const float bval = bias ? bias[col] : 0.0f;
      const size_t base = cOff + (size_t)(mBase + rowL) * ldc + col;
#pragma unroll
      for (int r = 0; r < 4; r++) {
        const float v = acc[i][j][r] + bval;
        if (Cb) Cb[base + (size_t)r * ldc] = f2bf(v);
        if (Cf) Cf[base + (size_t)r * ldc] = v;
      }
    }
  }
}

// ---------------- fused scores + mask + softmax + PV ---------------------------------
// Block: one (b,h), 16 query rows, full 1024 keys. 4 waves x 256-col slices.
// Scores live in registers (acc[16]); softmax reduces over the 16-lane col dim via
// shuffles, cross-wave via tiny LDS. Then normalized P is round-tripped through a
// swizzled LDS tile ([16][1024] bf16, byte ^= (row&7)<<4 to kill the 16-way
// ds_read_b128 bank conflict) and multiplied against vvT (L2-resident, read from
// global per lesson #7) to produce atp directly — this removes the 512 MB att
// re-read + the skinny N=128 PV GEMM dispatch entirely.
__global__ __launch_bounds__(256, 2) void scores_softmax_pv(
    const u16* __restrict__ qb, const u16* __restrict__ kb,
    const int* __restrict__ mask, const u16* __restrict__ vvT,
    float* __restrict__ att, u16* __restrict__ atp) {
  __shared__ int msk[1024];
  __shared__ float redM[4][16];
  __shared__ float redS[4][16];
  __shared__ __align__(16) u16 p_lds[16 * 1024];  // swizzled P tile (32 KB)
  const int tid = threadIdx.x;
  const int rowBlk = blockIdx.x, bh = blockIdx.y;
  const int b = bh >> 3, h = bh & 7;
  const int wid = tid >> 6, lane = tid & 63;
  const int lm = lane & 15, lq = lane >> 4;
  const int rowG = rowBlk * 16;

  *(int4*)&msk[tid * 4] = *(const int4*)(mask + (size_t)b * KK + tid * 4);

  // q fragments: 16 rows x dk=128 (4 k-steps), held in regs
  short8 qf[4];
  const u16* qp = qb + (size_t)(b * KK + rowG + lm) * NH + h * DK + lq * 8;
#pragma unroll
  for (int ks = 0; ks < 4; ks++) qf[ks] = *(const short8*)(qp + ks * 32);

  floatx4 acc[16] = {};
  const u16* kpB = kb + (size_t)(b * KK + wid * 256 + lm) * NH + h * DK + lq * 8;
#pragma unroll
  for (int jt = 0; jt < 16; jt++) {
    const u16* kp = kpB + (size_t)jt * 16 * NH;
    short8 k0 = *(const short8*)(kp + 0);
    short8 k1 = *(const short8*)(kp + 32);
    short8 k2 = *(const short8*)(kp + 64);
    short8 k3 = *(const short8*)(kp + 96);
    floatx4 a = acc[jt];
    a = MFMA16(qf[0], k0, a);
    a = MFMA16(qf[1], k1, a);
    a = MFMA16(qf[2], k2, a);
    a = MFMA16(qf[3], k3, a);
    acc[jt] = a;
  }
  __syncthreads();  // msk stores complete

  const float scale = 0.08838834764831845f;  // 1/sqrt(128)
  float mrow[4] = {-3e38f, -3e38f, -3e38f, -3e38f};
#pragma unroll
  for (int jt = 0; jt < 16; jt++) {
    const int col = wid * 256 + jt * 16 + lm;
    const bool mk = msk[col] != 0;
#pragma unroll
    for (int r = 0; r < 4; r++) {
      float s = mk ? -1e9f : acc[jt][r] * scale;
      acc[jt][r] = s;
      mrow[r] = fmaxf(mrow[r], s);
    }
  }
  // reduce max over the 16 lanes holding this row's cols
#pragma unroll
  for (int off = 1; off < 16; off <<= 1)
#pragma unroll
    for (int r = 0; r < 4; r++) mrow[r] = fmaxf(mrow[r], __shfl_xor(mrow[r], off));
  if (lm == 0) {
#pragma unroll
    for (int r = 0; r < 4; r++) redM[wid][lq * 4 + r] = mrow[r];
  }
  __syncthreads();
#pragma unroll
  for (int r = 0; r < 4; r++)
    mrow[r] = fmaxf(fmaxf(redM[0][lq * 4 + r], redM[1][lq * 4 + r]),
                    fmaxf(redM[2][lq * 4 + r], redM[3][lq * 4 + r]));

  float srow[4] = {0.f, 0.f, 0.f, 0.f};
#pragma unroll
  for (int jt = 0; jt < 16; jt++)
#pragma unroll
    for (int r = 0; r < 4; r++) {
      float e = __expf(acc[jt][r] - mrow[r]);
      acc[jt][r] = e;
      srow[r] += e;
    }
#pragma unroll
  for (int off = 1; off < 16; off <<= 1)
#pragma unroll
    for (int r = 0; r < 4; r++) srow[r] += __shfl_xor(srow[r], off);
  if (lm == 0) {
#pragma unroll
    for (int r = 0; r < 4; r++) redS[wid][lq * 4 + r] = srow[r];
  }
  __syncthreads();
#pragma unroll
  for (int r = 0; r < 4; r++) {
    float s = redS[0][lq * 4 + r] + redS[1][lq * 4 + r] +
              redS[2][lq * 4 + r] + redS[3][lq * 4 + r];
    srow[r] = 1.0f / s;
  }

  // normalize; store att (f32, nontemporal — write-once output) and P (bf16) to LDS.
  // LDS swizzle in u16 units: idx = (row*1024 + col) ^ ((row&7)<<3).
#pragma unroll
  for (int jt = 0; jt < 16; jt++) {
    const int col = wid * 256 + jt * 16 + lm;
#pragma unroll
    for (int r = 0; r < 4; r++) {
      const int row = lq * 4 + r;
      const float p = acc[jt][r] * srow[r];
      __builtin_nontemporal_store(
          p, &att[((size_t)bh * KK + rowG + row) * KK + col]);
      p_lds[(row * 1024 + col) ^ ((row & 7) << 3)] = f2bf(p);
    }
  }
  __syncthreads();  // P tile complete

  // PV: out tile 16 rows x 128 d; wave wid owns d-range [wid*32, wid*32+32).
  // A-frag: lane(lm=q-row, lq*8=k) from swizzled LDS. B-frag: vvT[bh][d][k] rows.
  floatx4 pacc[2] = {};
  const u16* vBase = vvT + (size_t)bh * DK * KK + (size_t)(wid * 32 + lm) * KK + lq * 8;
#pragma unroll 4
  for (int k0 = 0; k0 < KK; k0 += 32) {
    short8 pf = *(const short8*)&p_lds[(lm * 1024 + k0 + lq * 8) ^ ((lm & 7) << 3)];
    short8 v0 = *(const short8*)(vBase + k0);
    short8 v1 = *(const short8*)(vBase + 16 * KK + k0);
    pacc[0] = MFMA16(pf, v0, pacc[0]);
    pacc[1] = MFMA16(pf, v1, pacc[1]);
  }

  // epilogue: C layout col(d)=lm, row=lq*4+r; atp[b*K + row][h*128 + d] bf16
#pragma unroll
  for (int ct = 0; ct < 2; ct++) {
#pragma unroll
    for (int r = 0; r < 4; r++) {
      const int row = rowG + lq * 4 + r;
      const int d = h * DK + wid * 32 + ct * 16 + lm;
      atp[(size_t)(b * KK + row) * NH + d] = f2bf(pacc[ct][r]);
    }
  }
}

// ---------------- launcher ----------------------------------------------------------
extern "C" void kernel_launch(void* const* d_in, const int* in_sizes, int n_in,
                              void* d_out, int out_size, void* d_ws, size_t ws_size,
                              hipStream_t stream) {
  const float* v     = (const float*)d_in[0];
  const float* key   = (const float*)d_in[1];
  const float* query = (const float*)d_in[2];
  const int*   mask  = (const int*)d_in[3];
  const float* Wq = (const float*)d_in[4];
  const float* bq = (const float*)d_in[5];
  const float* Wk = (const float*)d_in[6];
  const float* bk = (const float*)d_in[7];
  const float* Wv = (const float*)d_in[8];
  const float* bv = (const float*)d_in[9];
  const float* Wm = (const float*)d_in[10];
  const float* bm = (const float*)d_in[11];

  float* atted = (float*)d_out;
  float* att   = atted + (size_t)ATT_OFF;

  // workspace layout (bytes): needs ~176 MB
  char* ws = (char*)d_ws;
  u16* qb   = (u16*)(ws + 0);
  u16* kb   = (u16*)(ws + 33554432ll);
  u16* vvb  = (u16*)(ws + 67108864ll);
  u16* vvT  = (u16*)(ws + 100663296ll);
  u16* atp  = (u16*)(ws + 134217728ll);
  u16* WqT  = (u16*)(ws + 167772160ll);
  u16* WkT  = (u16*)(ws + 169869312ll);
  u16* WvT  = (u16*)(ws + 171966464ll);
  u16* WmT  = (u16*)(ws + 174063616ll);

  // 1) weight transposes (f32 -> bf16, [k][n] -> [n][k])
  tr_w<<<dim3(32, 32), 256, 0, stream>>>(Wq, WqT);
  tr_w<<<dim3(32, 32), 256, 0, stream>>>(Wk, WkT);
  tr_w<<<dim3(32, 32), 256, 0, stream>>>(Wv, WvT);
  tr_w<<<dim3(32, 32), 256, 0, stream>>>(Wm, WmT);

  // 2) projections: [16384,1024] x [1024,1024] -> bf16
  gemm_bt<false><<<dim3(8, 128, 1), 256, 0, stream>>>(query, WqT, bq, qb, nullptr,
                                                      1024, 1024, 0, 0, 0, 0);
  gemm_bt<false><<<dim3(8, 128, 1), 256, 0, stream>>>(key, WkT, bk, kb, nullptr,
                                                      1024, 1024, 0, 0, 0, 0);
  gemm_bt<false><<<dim3(8, 128, 1), 256, 0, stream>>>(v, WvT, bv, vvb, nullptr,
                                                      1024, 1024, 0, 0, 0, 0);

  // 3) vv -> vvT[bh][d][k]
  tr_head<<<dim3(32, 4, 128), 256, 0, stream>>>(vvb, vvT);

  // 4) fused scores + mask + softmax -> att (f32) AND att@vv -> atp (bf16)
  scores_softmax_pv<<<dim3(64, 128), 256, 0, stream>>>(qb, kb, mask, vvT, att, atp);

  // 5) output projection: atp bf16 [16384,1024] x WmT -> atted f32
  gemm_bt<true><<<dim3(8, 128, 1), 256, 0, stream>>>(atp, WmT, bm, nullptr, atted,
                                                     1024, 1024, 0, 0, 0, 0);
}

// Round 2
// 1367.388 us; speedup vs baseline: 1.1484x; 1.1484x over previous
//
#include <hip/hip_runtime.h>

typedef unsigned short u16;
typedef __attribute__((ext_vector_type(8))) short short8;   // 8 x bf16 frag (4 VGPRs)
typedef __attribute__((ext_vector_type(4))) float floatx4;  // MFMA accumulator

#define MFMA16(a, b, c) __builtin_amdgcn_mfma_f32_16x16x32_bf16(a, b, c, 0, 0, 0)

// Problem constants
#define BB 16
#define KK 1024
#define NH 1024
#define HD 8
#define DK 128
#define ATT_OFF 16777216      // atted elems (16*1024*1024) before att in d_out

typedef const __attribute__((address_space(1))) unsigned gl_u32;
typedef __attribute__((address_space(3))) unsigned lds_u32;

__device__ __forceinline__ u16 f2bf(float x) {  // RNE f32 -> bf16
  unsigned u = __builtin_bit_cast(unsigned, x);
  u += 0x7fffu + ((u >> 16) & 1u);
  return (u16)(u >> 16);
}

// async global->LDS, 16B per lane; LDS dest must be wave-uniform base (HW adds lane*16)
__device__ __forceinline__ void gload16(const u16* g, u16* l) {
  __builtin_amdgcn_global_load_lds((gl_u32*)g, (lds_u32*)l, 16, 0, 0);
}

// ---------------- input cast: f32 -> bf16, 8 elems/thread ---------------------------
__global__ __launch_bounds__(256) void cast_bf16x8(const float* __restrict__ in,
                                                   u16* __restrict__ out) {
  const size_t i = ((size_t)blockIdx.x * 256 + threadIdx.x) * 8;
  float4 f0 = *(const float4*)(in + i);
  float4 f1 = *(const float4*)(in + i + 4);
  union { u16 u[8]; uint4 v; } p;
  p.u[0] = f2bf(f0.x); p.u[1] = f2bf(f0.y); p.u[2] = f2bf(f0.z); p.u[3] = f2bf(f0.w);
  p.u[4] = f2bf(f1.x); p.u[5] = f2bf(f1.y); p.u[6] = f2bf(f1.z); p.u[7] = f2bf(f1.w);
  *(uint4*)(out + i) = p.v;
}

// ---------------- weight transpose+cast: in f32 [1024][1024] -> out bf16 [n][k] ----
__global__ __launch_bounds__(256) void tr_w(const float* __restrict__ in,
                                            u16* __restrict__ out) {
  __shared__ u16 t[32][36];
  const int tid = threadIdx.x;
  const int bx = blockIdx.x * 32;  // n base
  const int by = blockIdx.y * 32;  // k base
  const int r = tid >> 3, c4 = (tid & 7) * 4;
  float4 f = *(const float4*)(in + (size_t)(by + r) * 1024 + bx + c4);
  t[r][c4 + 0] = f2bf(f.x);
  t[r][c4 + 1] = f2bf(f.y);
  t[r][c4 + 2] = f2bf(f.z);
  t[r][c4 + 3] = f2bf(f.w);
  __syncthreads();
  union { u16 u[4]; uint2 v; } p;
#pragma unroll
  for (int i = 0; i < 4; i++) p.u[i] = t[c4 + i][r];
  *(uint2*)(out + (size_t)(bx + r) * 1024 + by + c4) = p.v;  // out[n][k] = in[k][n]
}

// ---------------- vv head transpose: vvb bf16 [b,i,h*128+d] -> vvT [bh][d][i] -------
__global__ __launch_bounds__(256) void tr_head(const u16* __restrict__ vvb,
                                               u16* __restrict__ vvT) {
  __shared__ u16 t[32][36];
  const int tid = threadIdx.x;
  const int bh = blockIdx.z, b = bh >> 3, h = bh & 7;
  const int i0 = blockIdx.x * 32, d0 = blockIdx.y * 32;
  const int r = tid >> 3, c4 = (tid & 7) * 4;
  union { u16 u[4]; uint2 v; } p;
  p.v = *(const uint2*)(vvb + (size_t)(b * KK + i0 + r) * NH + h * DK + d0 + c4);
  t[r][c4 + 0] = p.u[0];
  t[r][c4 + 1] = p.u[1];
  t[r][c4 + 2] = p.u[2];
  t[r][c4 + 3] = p.u[3];
  __syncthreads();
#pragma unroll
  for (int i = 0; i < 4; i++) p.u[i] = t[c4 + i][r];
  *(uint2*)(vvT + (size_t)(bh * DK + d0 + r) * KK + i0 + c4) = p.v;
}

// ---------------- MFMA GEMM (m97 structure): C = A[M,Kd] * Bt[N,Kd]^T (+bias) -------
// A and Bt bf16, k-contiguous rows. Tile 128x128x32, 4 waves 2x2, each wave 64x64.
// Staging: global_load_lds width-16 into LINEAR [128][32] LDS tiles (no VGPR trip).
__global__ __launch_bounds__(256, 2) void gemm_bt(
    const u16* __restrict__ A, const u16* __restrict__ Bt,
    const float* __restrict__ bias, u16* __restrict__ Cb, float* __restrict__ Cf,
    int Kd, int ldc, long long aBatch, long long btBatch,
    long long cBatchB, long long cBatchH) {
  __shared__ __align__(16) u16 As[128 * 32];
  __shared__ __align__(16) u16 Bs[128 * 32];
  const int tid = threadIdx.x;
  const int z = blockIdx.z;
  const int nBase = blockIdx.x * 128;
  const int mBase = blockIdx.y * 128;
  const u16* Ab = A + (size_t)z * aBatch;
  const u16* Bb = Bt + (size_t)z * btBatch;
  const size_t cOff = (size_t)(z >> 3) * cBatchB + (size_t)(z & 7) * cBatchH;

  const int wid = tid >> 6, lane = tid & 63;
  const int wm = (wid & 1) * 64, wn = (wid >> 1) * 64;
  const int lm = lane & 15, lq = lane >> 4;

  // staging: instr t (0/1) of this wave covers rows (wid*2+t)*16 + lane/4,
  // 16B k-slot (lane&3)*8. LDS dest = wave-uniform base (+ lane*16 by HW).
  const int rIn = lane >> 2;            // row within 16-row group
  const int sSlot = (lane & 3) * 8;     // k-offset in u16
  u16* aDst0 = &As[(wid * 2 + 0) * 512];
  u16* aDst1 = &As[(wid * 2 + 1) * 512];
  u16* bDst0 = &Bs[(wid * 2 + 0) * 512];
  u16* bDst1 = &Bs[(wid * 2 + 1) * 512];
  const u16* aSrc0 = Ab + (size_t)(mBase + (wid * 2 + 0) * 16 + rIn) * Kd + sSlot;
  const u16* aSrc1 = Ab + (size_t)(mBase + (wid * 2 + 1) * 16 + rIn) * Kd + sSlot;
  const u16* bSrc0 = Bb + (size_t)(nBase + (wid * 2 + 0) * 16 + rIn) * Kd + sSlot;
  const u16* bSrc1 = Bb + (size_t)(nBase + (wid * 2 + 1) * 16 + rIn) * Kd + sSlot;

  floatx4 acc[4][4] = {};

  for (int k0 = 0; k0 < Kd; k0 += 32) {
    gload16(aSrc0 + k0, aDst0);
    gload16(aSrc1 + k0, aDst1);
    gload16(bSrc0 + k0, bDst0);
    gload16(bSrc1 + k0, bDst1);
    __syncthreads();  // drains vmcnt -> staged data visible

    short8 af[4], bfr[4];
#pragma unroll
    for (int t = 0; t < 4; t++) {
      af[t]  = *(const short8*)&As[(wm + t * 16 + lm) * 32 + lq * 8];
      bfr[t] = *(const short8*)&Bs[(wn + t * 16 + lm) * 32 + lq * 8];
    }
#pragma unroll
    for (int i = 0; i < 4; i++)
#pragma unroll
      for (int j = 0; j < 4; j++)
        acc[i][j] = MFMA16(af[i], bfr[j], acc[i][j]);
    __syncthreads();  // all reads done before next stage overwrites
  }

  // epilogue: C/D layout col=lane&15, row=(lane>>4)*4+reg
#pragma unroll
  for (int i = 0; i < 4; i++) {
    const int rowL = wm + i * 16 + lq * 4;
#pragma unroll
    for (int j = 0; j < 4; j++) {
      const int col = nBase + wn + j * 16 + lm;
      const float bval = bias ? bias[col] : 0.0f;
      const size_t base = cOff + (size_t)(mBase + rowL) * ldc + col;
#pragma unroll
      for (int r = 0; r < 4; r++) {
        const float v = acc[i][j][r] + bval;
        if (Cb) Cb[base + (size_t)r * ldc] = f2bf(v);
        if (Cf) Cf[base + (size_t)r * ldc] = v;
      }
    }
  }
}

// ---------------- fused scores + mask + softmax + PV ---------------------------------
// Block: one (b,h), 16 query rows, full 1024 keys. 4 waves x 256-col slices.
// LDS is EXACTLY 32768 B (5 blocks/CU): p_lds doubles as mask (u16, [0..1024)) and
// redM/redS (f32, [1024..1280)) scratch — both dead before P-tile writes; the extra
// __syncthreads after the redS read protects the alias.
__global__ __launch_bounds__(256, 2) void scores_softmax_pv(
    const u16* __restrict__ qb, const u16* __restrict__ kb,
    const int* __restrict__ mask, const u16* __restrict__ vvT,
    float* __restrict__ att, u16* __restrict__ atp) {
  __shared__ __align__(16) u16 p_lds[16 * 1024];  // 32 KB total
  u16* msk16 = p_lds;                    // [0..1024) u16
  float* redM = (float*)&p_lds[1024];    // 64 f32
  float* redS = (float*)&p_lds[1152];    // 64 f32
  const int tid = threadIdx.x;
  const int rowBlk = blockIdx.x, bh = blockIdx.y;
  const int b = bh >> 3, h = bh & 7;
  const int wid = tid >> 6, lane = tid & 63;
  const int lm = lane & 15, lq = lane >> 4;
  const int rowG = rowBlk * 16;

  {
    int4 m = *(const int4*)(mask + (size_t)b * KK + tid * 4);
    msk16[tid * 4 + 0] = (u16)(m.x != 0);
    msk16[tid * 4 + 1] = (u16)(m.y != 0);
    msk16[tid * 4 + 2] = (u16)(m.z != 0);
    msk16[tid * 4 + 3] = (u16)(m.w != 0);
  }

  // q fragments: 16 rows x dk=128 (4 k-steps), held in regs
  short8 qf[4];
  const u16* qp = qb + (size_t)(b * KK + rowG + lm) * NH + h * DK + lq * 8;
#pragma unroll
  for (int ks = 0; ks < 4; ks++) qf[ks] = *(const short8*)(qp + ks * 32);

  floatx4 acc[16] = {};
  const u16* kpB = kb + (size_t)(b * KK + wid * 256 + lm) * NH + h * DK + lq * 8;
#pragma unroll
  for (int jt = 0; jt < 16; jt++) {
    const u16* kp = kpB + (size_t)jt * 16 * NH;
    short8 k0 = *(const short8*)(kp + 0);
    short8 k1 = *(const short8*)(kp + 32);
    short8 k2 = *(const short8*)(kp + 64);
    short8 k3 = *(const short8*)(kp + 96);
    floatx4 a = acc[jt];
    a = MFMA16(qf[0], k0, a);
    a = MFMA16(qf[1], k1, a);
    a = MFMA16(qf[2], k2, a);
    a = MFMA16(qf[3], k3, a);
    acc[jt] = a;
  }
  __syncthreads();  // msk stores complete

  const float scale = 0.08838834764831845f;  // 1/sqrt(128)
  float mrow[4] = {-3e38f, -3e38f, -3e38f, -3e38f};
#pragma unroll
  for (int jt = 0; jt < 16; jt++) {
    const int col = wid * 256 + jt * 16 + lm;
    const bool mk = msk16[col] != 0;
#pragma unroll
    for (int r = 0; r < 4; r++) {
      float s = mk ? -1e9f : acc[jt][r] * scale;
      acc[jt][r] = s;
      mrow[r] = fmaxf(mrow[r], s);
    }
  }
  // reduce max over the 16 lanes holding this row's cols
#pragma unroll
  for (int off = 1; off < 16; off <<= 1)
#pragma unroll
    for (int r = 0; r < 4; r++) mrow[r] = fmaxf(mrow[r], __shfl_xor(mrow[r], off));
  if (lm == 0) {
#pragma unroll
    for (int r = 0; r < 4; r++) redM[wid * 16 + lq * 4 + r] = mrow[r];
  }
  __syncthreads();
#pragma unroll
  for (int r = 0; r < 4; r++)
    mrow[r] = fmaxf(fmaxf(redM[0 + lq * 4 + r], redM[16 + lq * 4 + r]),
                    fmaxf(redM[32 + lq * 4 + r], redM[48 + lq * 4 + r]));

  float srow[4] = {0.f, 0.f, 0.f, 0.f};
#pragma unroll
  for (int jt = 0; jt < 16; jt++)
#pragma unroll
    for (int r = 0; r < 4; r++) {
      float e = __expf(acc[jt][r] - mrow[r]);
      acc[jt][r] = e;
      srow[r] += e;
    }
#pragma unroll
  for (int off = 1; off < 16; off <<= 1)
#pragma unroll
    for (int r = 0; r < 4; r++) srow[r] += __shfl_xor(srow[r], off);
  if (lm == 0) {
#pragma unroll
    for (int r = 0; r < 4; r++) redS[wid * 16 + lq * 4 + r] = srow[r];
  }
  __syncthreads();
#pragma unroll
  for (int r = 0; r < 4; r++) {
    float s = redS[0 + lq * 4 + r] + redS[16 + lq * 4 + r] +
              redS[32 + lq * 4 + r] + redS[48 + lq * 4 + r];
    srow[r] = 1.0f / s;
  }
  __syncthreads();  // alias protection: redS reads done before p_lds writes below

  // normalize; store att (f32, nontemporal — write-once output) and P (bf16) to LDS.
  // LDS swizzle in u16 units: idx = (row*1024 + col) ^ ((row&7)<<3).
#pragma unroll
  for (int jt = 0; jt < 16; jt++) {
    const int col = wid * 256 + jt * 16 + lm;
#pragma unroll
    for (int r = 0; r < 4; r++) {
      const int row = lq * 4 + r;
      const float p = acc[jt][r] * srow[r];
      __builtin_nontemporal_store(
          p, &att[((size_t)bh * KK + rowG + row) * KK + col]);
      p_lds[(row * 1024 + col) ^ ((row & 7) << 3)] = f2bf(p);
    }
  }
  __syncthreads();  // P tile complete

  // PV: out tile 16 rows x 128 d; wave wid owns d-range [wid*32, wid*32+32).
  // 4 independent MFMA chains (k split in halves) to break dependent-MFMA latency.
  floatx4 pacc0 = {}, pacc1 = {}, pacc2 = {}, pacc3 = {};
  const u16* vBase = vvT + (size_t)bh * DK * KK + (size_t)(wid * 32 + lm) * KK + lq * 8;
#pragma unroll 4
  for (int k0 = 0; k0 < 512; k0 += 32) {
    short8 pfa = *(const short8*)&p_lds[(lm * 1024 + k0 + lq * 8) ^ ((lm & 7) << 3)];
    short8 pfb = *(const short8*)&p_lds[(lm * 1024 + 512 + k0 + lq * 8) ^ ((lm & 7) << 3)];
    short8 v0a = *(const short8*)(vBase + k0);
    short8 v1a = *(const short8*)(vBase + 16 * KK + k0);
    short8 v0b = *(const short8*)(vBase + 512 + k0);
    short8 v1b = *(const short8*)(vBase + 16 * KK + 512 + k0);
    pacc0 = MFMA16(pfa, v0a, pacc0);
    pacc1 = MFMA16(pfa, v1a, pacc1);
    pacc2 = MFMA16(pfb, v0b, pacc2);
    pacc3 = MFMA16(pfb, v1b, pacc3);
  }
  floatx4 o0 = pacc0 + pacc2;
  floatx4 o1 = pacc1 + pacc3;

  // epilogue: C layout col(d)=lm, row=lq*4+r; atp[b*K + row][h*128 + d] bf16
#pragma unroll
  for (int r = 0; r < 4; r++) {
    const int row = rowG + lq * 4 + r;
    atp[(size_t)(b * KK + row) * NH + h * DK + wid * 32 + 0 + lm] = f2bf(o0[r]);
    atp[(size_t)(b * KK + row) * NH + h * DK + wid * 32 + 16 + lm] = f2bf(o1[r]);
  }
}

// ---------------- launcher ----------------------------------------------------------
extern "C" void kernel_launch(void* const* d_in, const int* in_sizes, int n_in,
                              void* d_out, int out_size, void* d_ws, size_t ws_size,
                              hipStream_t stream) {
  const float* v     = (const float*)d_in[0];
  const float* key   = (const float*)d_in[1];
  const float* query = (const float*)d_in[2];
  const int*   mask  = (const int*)d_in[3];
  const float* Wq = (const float*)d_in[4];
  const float* bq = (const float*)d_in[5];
  const float* Wk = (const float*)d_in[6];
  const float* bk = (const float*)d_in[7];
  const float* Wv = (const float*)d_in[8];
  const float* bv = (const float*)d_in[9];
  const float* Wm = (const float*)d_in[10];
  const float* bm = (const float*)d_in[11];

  float* atted = (float*)d_out;
  float* att   = atted + (size_t)ATT_OFF;

  // workspace layout (bytes): ~176 MB, unchanged
  char* ws = (char*)d_ws;
  u16* qb   = (u16*)(ws + 0);
  u16* kb   = (u16*)(ws + 33554432ll);
  u16* vvb  = (u16*)(ws + 67108864ll);
  u16* vvT  = (u16*)(ws + 100663296ll);
  u16* atp  = (u16*)(ws + 134217728ll);
  u16* WqT  = (u16*)(ws + 167772160ll);
  u16* WkT  = (u16*)(ws + 169869312ll);
  u16* WvT  = (u16*)(ws + 171966464ll);
  u16* WmT  = (u16*)(ws + 174063616ll);

  // bf16 copies of raw inputs live in the (not yet written) att region of d_out:
  // all dead before scores_softmax_pv overwrites att. Zero workspace growth.
  u16* cq = (u16*)att;
  u16* ck = cq + 16777216;
  u16* cv = ck + 16777216;

  // 0) input casts f32 -> bf16 (16M elems each, 8/thread)
  cast_bf16x8<<<8192, 256, 0, stream>>>(query, cq);
  cast_bf16x8<<<8192, 256, 0, stream>>>(key, ck);
  cast_bf16x8<<<8192, 256, 0, stream>>>(v, cv);

  // 1) weight transposes (f32 -> bf16, [k][n] -> [n][k])
  tr_w<<<dim3(32, 32), 256, 0, stream>>>(Wq, WqT);
  tr_w<<<dim3(32, 32), 256, 0, stream>>>(Wk, WkT);
  tr_w<<<dim3(32, 32), 256, 0, stream>>>(Wv, WvT);
  tr_w<<<dim3(32, 32), 256, 0, stream>>>(Wm, WmT);

  // 2) projections: [16384,1024] x [1024,1024] -> bf16 (all-bf16 gl_lds GEMM)
  gemm_bt<<<dim3(8, 128, 1), 256, 0, stream>>>(cq, WqT, bq, qb, nullptr,
                                               1024, 1024, 0, 0, 0, 0);
  gemm_bt<<<dim3(8, 128, 1), 256, 0, stream>>>(ck, WkT, bk, kb, nullptr,
                                               1024, 1024, 0, 0, 0, 0);
  gemm_bt<<<dim3(8, 128, 1), 256, 0, stream>>>(cv, WvT, bv, vvb, nullptr,
                                               1024, 1024, 0, 0, 0, 0);

  // 3) vv -> vvT[bh][d][k]
  tr_head<<<dim3(32, 4, 128), 256, 0, stream>>>(vvb, vvT);

  // 4) fused scores + mask + softmax -> att (f32) AND att@vv -> atp (bf16)
  scores_softmax_pv<<<dim3(64, 128), 256, 0, stream>>>(qb, kb, mask, vvT, att, atp);

  // 5) output projection: atp bf16 [16384,1024] x WmT -> atted f32
  gemm_bt<<<dim3(8, 128, 1), 256, 0, stream>>>(atp, WmT, bm, nullptr, atted,
                                               1024, 1024, 0, 0, 0, 0);
}

// Round 3
// 1337.208 us; speedup vs baseline: 1.1743x; 1.0226x over previous
//
#include <hip/hip_runtime.h>

typedef unsigned short u16;
typedef __attribute__((ext_vector_type(8))) short short8;   // 8 x bf16 frag (4 VGPRs)
typedef __attribute__((ext_vector_type(4))) float floatx4;  // MFMA accumulator

#define MFMA16(a, b, c) __builtin_amdgcn_mfma_f32_16x16x32_bf16(a, b, c, 0, 0, 0)

// Problem constants
#define BB 16
#define KK 1024
#define NH 1024
#define HD 8
#define DK 128
#define ATT_OFF 16777216      // atted elems (16*1024*1024) before att in d_out

typedef const __attribute__((address_space(1))) unsigned gl_u32;
typedef __attribute__((address_space(3))) unsigned lds_u32;

__device__ __forceinline__ u16 f2bf(float x) {  // RNE f32 -> bf16
  unsigned u = __builtin_bit_cast(unsigned, x);
  u += 0x7fffu + ((u >> 16) & 1u);
  return (u16)(u >> 16);
}

// async global->LDS, 16B per lane; LDS dest must be wave-uniform base (HW adds lane*16)
__device__ __forceinline__ void gload16(const u16* g, u16* l) {
  __builtin_amdgcn_global_load_lds((gl_u32*)g, (lds_u32*)l, 16, 0, 0);
}

// ---------------- input cast: f32 -> bf16, 8 elems/thread ---------------------------
__global__ __launch_bounds__(256) void cast_bf16x8(const float* __restrict__ in,
                                                   u16* __restrict__ out) {
  const size_t i = ((size_t)blockIdx.x * 256 + threadIdx.x) * 8;
  float4 f0 = *(const float4*)(in + i);
  float4 f1 = *(const float4*)(in + i + 4);
  union { u16 u[8]; uint4 v; } p;
  p.u[0] = f2bf(f0.x); p.u[1] = f2bf(f0.y); p.u[2] = f2bf(f0.z); p.u[3] = f2bf(f0.w);
  p.u[4] = f2bf(f1.x); p.u[5] = f2bf(f1.y); p.u[6] = f2bf(f1.z); p.u[7] = f2bf(f1.w);
  *(uint4*)(out + i) = p.v;
}

// ---------------- weight transpose+cast: in f32 [1024][1024] -> out bf16 [n][k] ----
__global__ __launch_bounds__(256) void tr_w(const float* __restrict__ in,
                                            u16* __restrict__ out) {
  __shared__ u16 t[32][36];
  const int tid = threadIdx.x;
  const int bx = blockIdx.x * 32;  // n base
  const int by = blockIdx.y * 32;  // k base
  const int r = tid >> 3, c4 = (tid & 7) * 4;
  float4 f = *(const float4*)(in + (size_t)(by + r) * 1024 + bx + c4);
  t[r][c4 + 0] = f2bf(f.x);
  t[r][c4 + 1] = f2bf(f.y);
  t[r][c4 + 2] = f2bf(f.z);
  t[r][c4 + 3] = f2bf(f.w);
  __syncthreads();
  union { u16 u[4]; uint2 v; } p;
#pragma unroll
  for (int i = 0; i < 4; i++) p.u[i] = t[c4 + i][r];
  *(uint2*)(out + (size_t)(bx + r) * 1024 + by + c4) = p.v;  // out[n][k] = in[k][n]
}

// ---------------- vv head transpose: vvb bf16 [b,i,h*128+d] -> vvT [bh][d][i] -------
__global__ __launch_bounds__(256) void tr_head(const u16* __restrict__ vvb,
                                               u16* __restrict__ vvT) {
  __shared__ u16 t[32][36];
  const int tid = threadIdx.x;
  const int bh = blockIdx.z, b = bh >> 3, h = bh & 7;
  const int i0 = blockIdx.x * 32, d0 = blockIdx.y * 32;
  const int r = tid >> 3, c4 = (tid & 7) * 4;
  union { u16 u[4]; uint2 v; } p;
  p.v = *(const uint2*)(vvb + (size_t)(b * KK + i0 + r) * NH + h * DK + d0 + c4);
  t[r][c4 + 0] = p.u[0];
  t[r][c4 + 1] = p.u[1];
  t[r][c4 + 2] = p.u[2];
  t[r][c4 + 3] = p.u[3];
  __syncthreads();
#pragma unroll
  for (int i = 0; i < 4; i++) p.u[i] = t[c4 + i][r];
  *(uint2*)(vvT + (size_t)(bh * DK + d0 + r) * KK + i0 + c4) = p.v;
}

// ---------------- MFMA GEMM (m97 structure): C = A[M,Kd] * Bt[N,Kd]^T (+bias) -------
// A and Bt bf16, k-contiguous rows. Tile 128x128x32, 4 waves 2x2, each wave 64x64.
// Staging: global_load_lds width-16 into LINEAR [128][32] LDS tiles (no VGPR trip).
// T1 XCD swizzle (nwg=1024): XCD x owns mBase stripe [16x,16x+16), A-panels L2-resident.
__global__ __launch_bounds__(256, 2) void gemm_bt(
    const u16* __restrict__ A, const u16* __restrict__ Bt,
    const float* __restrict__ bias, u16* __restrict__ Cb, float* __restrict__ Cf,
    int Kd, int ldc, long long aBatch, long long btBatch,
    long long cBatchB, long long cBatchH) {
  __shared__ __align__(16) u16 As[128 * 32];
  __shared__ __align__(16) u16 Bs[128 * 32];
  const int tid = threadIdx.x;
  const int z = blockIdx.z;

  int bxs = blockIdx.x, bys = blockIdx.y;
  if (gridDim.x == 8 && gridDim.y == 128 && gridDim.z == 1) {
    const int flat = blockIdx.x + 8 * blockIdx.y;   // 0..1023, round-robin XCDs
    const int xcd = flat & 7, idx = flat >> 3;      // idx 0..127 within XCD
    const int nflat = xcd * 128 + idx;              // contiguous chunk per XCD
    bxs = nflat & 7;
    bys = nflat >> 3;                               // [16*xcd, 16*xcd+16)
  }
  const int nBase = bxs * 128;
  const int mBase = bys * 128;

  const u16* Ab = A + (size_t)z * aBatch;
  const u16* Bb = Bt + (size_t)z * btBatch;
  const size_t cOff = (size_t)(z >> 3) * cBatchB + (size_t)(z & 7) * cBatchH;

  const int wid = tid >> 6, lane = tid & 63;
  const int wm = (wid & 1) * 64, wn = (wid >> 1) * 64;
  const int lm = lane & 15, lq = lane >> 4;

  // staging: instr t (0/1) of this wave covers rows (wid*2+t)*16 + lane/4,
  // 16B k-slot (lane&3)*8. LDS dest = wave-uniform base (+ lane*16 by HW).
  const int rIn = lane >> 2;            // row within 16-row group
  const int sSlot = (lane & 3) * 8;     // k-offset in u16
  u16* aDst0 = &As[(wid * 2 + 0) * 512];
  u16* aDst1 = &As[(wid * 2 + 1) * 512];
  u16* bDst0 = &Bs[(wid * 2 + 0) * 512];
  u16* bDst1 = &Bs[(wid * 2 + 1) * 512];
  const u16* aSrc0 = Ab + (size_t)(mBase + (wid * 2 + 0) * 16 + rIn) * Kd + sSlot;
  const u16* aSrc1 = Ab + (size_t)(mBase + (wid * 2 + 1) * 16 + rIn) * Kd + sSlot;
  const u16* bSrc0 = Bb + (size_t)(nBase + (wid * 2 + 0) * 16 + rIn) * Kd + sSlot;
  const u16* bSrc1 = Bb + (size_t)(nBase + (wid * 2 + 1) * 16 + rIn) * Kd + sSlot;

  floatx4 acc[4][4] = {};

  for (int k0 = 0; k0 < Kd; k0 += 32) {
    gload16(aSrc0 + k0, aDst0);
    gload16(aSrc1 + k0, aDst1);
    gload16(bSrc0 + k0, bDst0);
    gload16(bSrc1 + k0, bDst1);
    __syncthreads();  // drains vmcnt -> staged data visible

    short8 af[4], bfr[4];
#pragma unroll
    for (int t = 0; t < 4; t++) {
      af[t]  = *(const short8*)&As[(wm + t * 16 + lm) * 32 + lq * 8];
      bfr[t] = *(const short8*)&Bs[(wn + t * 16 + lm) * 32 + lq * 8];
    }
#pragma unroll
    for (int i = 0; i < 4; i++)
#pragma unroll
      for (int j = 0; j < 4; j++)
        acc[i][j] = MFMA16(af[i], bfr[j], acc[i][j]);
    __syncthreads();  // all reads done before next stage overwrites
  }

  // epilogue: C/D layout col=lane&15, row=(lane>>4)*4+reg
#pragma unroll
  for (int i = 0; i < 4; i++) {
    const int rowL = wm + i * 16 + lq * 4;
#pragma unroll
    for (int j = 0; j < 4; j++) {
      const int col = nBase + wn + j * 16 + lm;
      const float bval = bias ? bias[col] : 0.0f;
      const size_t base = cOff + (size_t)(mBase + rowL) * ldc + col;
#pragma unroll
      for (int r = 0; r < 4; r++) {
        const float v = acc[i][j][r] + bval;
        if (Cb) Cb[base + (size_t)r * ldc] = f2bf(v);
        if (Cf) Cf[base + (size_t)r * ldc] = v;
      }
    }
  }
}

// ---------------- fused scores + mask + softmax + PV ---------------------------------
// Block: one (b,h), 16 query rows, full 1024 keys. 4 waves x 256-col slices.
// T1 XCD swizzle: XCD x owns bh in [16x,16x+16), all 64 rowBlks of a bh consecutive
// -> kb/vvT slices (512 KB/bh) become L2-resident instead of L3/HBM re-streamed.
// LDS is EXACTLY 32768 B: p_lds doubles as mask (u16) and redM/redS scratch.
__global__ __launch_bounds__(256, 2) void scores_softmax_pv(
    const u16* __restrict__ qb, const u16* __restrict__ kb,
    const int* __restrict__ mask, const u16* __restrict__ vvT,
    float* __restrict__ att, u16* __restrict__ atp) {
  __shared__ __align__(16) u16 p_lds[16 * 1024];  // 32 KB total
  u16* msk16 = p_lds;                    // [0..1024) u16
  float* redM = (float*)&p_lds[1024];    // 64 f32
  float* redS = (float*)&p_lds[1152];    // 64 f32
  const int tid = threadIdx.x;

  // grid is (64,128): flat 0..8191 round-robins XCDs; give each XCD 16 bh groups,
  // rowBlk fastest within a bh so slice reuse is temporally tight.
  const int flat = blockIdx.x + 64 * blockIdx.y;
  const int xcd = flat & 7, idx = flat >> 3;       // idx 0..1023
  const int bh = xcd * 16 + (idx >> 6);
  const int rowBlk = idx & 63;

  const int b = bh >> 3, h = bh & 7;
  const int wid = tid >> 6, lane = tid & 63;
  const int lm = lane & 15, lq = lane >> 4;
  const int rowG = rowBlk * 16;

  {
    int4 m = *(const int4*)(mask + (size_t)b * KK + tid * 4);
    msk16[tid * 4 + 0] = (u16)(m.x != 0);
    msk16[tid * 4 + 1] = (u16)(m.y != 0);
    msk16[tid * 4 + 2] = (u16)(m.z != 0);
    msk16[tid * 4 + 3] = (u16)(m.w != 0);
  }

  // q fragments: 16 rows x dk=128 (4 k-steps), held in regs
  short8 qf[4];
  const u16* qp = qb + (size_t)(b * KK + rowG + lm) * NH + h * DK + lq * 8;
#pragma unroll
  for (int ks = 0; ks < 4; ks++) qf[ks] = *(const short8*)(qp + ks * 32);

  floatx4 acc[16] = {};
  const u16* kpB = kb + (size_t)(b * KK + wid * 256 + lm) * NH + h * DK + lq * 8;
#pragma unroll
  for (int jt = 0; jt < 16; jt++) {
    const u16* kp = kpB + (size_t)jt * 16 * NH;
    short8 k0 = *(const short8*)(kp + 0);
    short8 k1 = *(const short8*)(kp + 32);
    short8 k2 = *(const short8*)(kp + 64);
    short8 k3 = *(const short8*)(kp + 96);
    floatx4 a = acc[jt];
    a = MFMA16(qf[0], k0, a);
    a = MFMA16(qf[1], k1, a);
    a = MFMA16(qf[2], k2, a);
    a = MFMA16(qf[3], k3, a);
    acc[jt] = a;
  }
  __syncthreads();  // msk stores complete

  const float scale = 0.08838834764831845f;  // 1/sqrt(128)
  float mrow[4] = {-3e38f, -3e38f, -3e38f, -3e38f};
#pragma unroll
  for (int jt = 0; jt < 16; jt++) {
    const int col = wid * 256 + jt * 16 + lm;
    const bool mk = msk16[col] != 0;
#pragma unroll
    for (int r = 0; r < 4; r++) {
      float s = mk ? -1e9f : acc[jt][r] * scale;
      acc[jt][r] = s;
      mrow[r] = fmaxf(mrow[r], s);
    }
  }
  // reduce max over the 16 lanes holding this row's cols
#pragma unroll
  for (int off = 1; off < 16; off <<= 1)
#pragma unroll
    for (int r = 0; r < 4; r++) mrow[r] = fmaxf(mrow[r], __shfl_xor(mrow[r], off));
  if (lm == 0) {
#pragma unroll
    for (int r = 0; r < 4; r++) redM[wid * 16 + lq * 4 + r] = mrow[r];
  }
  __syncthreads();
#pragma unroll
  for (int r = 0; r < 4; r++)
    mrow[r] = fmaxf(fmaxf(redM[0 + lq * 4 + r], redM[16 + lq * 4 + r]),
                    fmaxf(redM[32 + lq * 4 + r], redM[48 + lq * 4 + r]));

  float srow[4] = {0.f, 0.f, 0.f, 0.f};
#pragma unroll
  for (int jt = 0; jt < 16; jt++)
#pragma unroll
    for (int r = 0; r < 4; r++) {
      float e = __expf(acc[jt][r] - mrow[r]);
      acc[jt][r] = e;
      srow[r] += e;
    }
#pragma unroll
  for (int off = 1; off < 16; off <<= 1)
#pragma unroll
    for (int r = 0; r < 4; r++) srow[r] += __shfl_xor(srow[r], off);
  if (lm == 0) {
#pragma unroll
    for (int r = 0; r < 4; r++) redS[wid * 16 + lq * 4 + r] = srow[r];
  }
  __syncthreads();
#pragma unroll
  for (int r = 0; r < 4; r++) {
    float s = redS[0 + lq * 4 + r] + redS[16 + lq * 4 + r] +
              redS[32 + lq * 4 + r] + redS[48 + lq * 4 + r];
    srow[r] = 1.0f / s;
  }
  __syncthreads();  // alias protection: redS reads done before p_lds writes below

  // normalize; store att (f32, nontemporal) and P (bf16) to LDS.
  // Loop order: r outer, jt inner -> per row, consecutive 64B chunks back-to-back
  // (write combining); was r inner = 4-row-strided partial lines.
  // LDS swizzle in u16 units: idx = (row*1024 + col) ^ ((row&7)<<3).
#pragma unroll
  for (int r = 0; r < 4; r++) {
    const int row = lq * 4 + r;
    float* attRow = att + ((size_t)bh * KK + rowG + row) * KK;
#pragma unroll
    for (int jt = 0; jt < 16; jt++) {
      const int col = wid * 256 + jt * 16 + lm;
      const float p = acc[jt][r] * srow[r];
      __builtin_nontemporal_store(p, attRow + col);
      p_lds[(row * 1024 + col) ^ ((row & 7) << 3)] = f2bf(p);
    }
  }
  __syncthreads();  // P tile complete

  // PV: out tile 16 rows x 128 d; wave wid owns d-range [wid*32, wid*32+32).
  // 4 independent MFMA chains (k split in halves) to break dependent-MFMA latency.
  floatx4 pacc0 = {}, pacc1 = {}, pacc2 = {}, pacc3 = {};
  const u16* vBase = vvT + (size_t)bh * DK * KK + (size_t)(wid * 32 + lm) * KK + lq * 8;
#pragma unroll 4
  for (int k0 = 0; k0 < 512; k0 += 32) {
    short8 pfa = *(const short8*)&p_lds[(lm * 1024 + k0 + lq * 8) ^ ((lm & 7) << 3)];
    short8 pfb = *(const short8*)&p_lds[(lm * 1024 + 512 + k0 + lq * 8) ^ ((lm & 7) << 3)];
    short8 v0a = *(const short8*)(vBase + k0);
    short8 v1a = *(const short8*)(vBase + 16 * KK + k0);
    short8 v0b = *(const short8*)(vBase + 512 + k0);
    short8 v1b = *(const short8*)(vBase + 16 * KK + 512 + k0);
    pacc0 = MFMA16(pfa, v0a, pacc0);
    pacc1 = MFMA16(pfa, v1a, pacc1);
    pacc2 = MFMA16(pfb, v0b, pacc2);
    pacc3 = MFMA16(pfb, v1b, pacc3);
  }
  floatx4 o0 = pacc0 + pacc2;
  floatx4 o1 = pacc1 + pacc3;

  // epilogue: C layout col(d)=lm, row=lq*4+r; atp[b*K + row][h*128 + d] bf16
#pragma unroll
  for (int r = 0; r < 4; r++) {
    const int row = rowG + lq * 4 + r;
    atp[(size_t)(b * KK + row) * NH + h * DK + wid * 32 + 0 + lm] = f2bf(o0[r]);
    atp[(size_t)(b * KK + row) * NH + h * DK + wid * 32 + 16 + lm] = f2bf(o1[r]);
  }
}

// ---------------- launcher ----------------------------------------------------------
extern "C" void kernel_launch(void* const* d_in, const int* in_sizes, int n_in,
                              void* d_out, int out_size, void* d_ws, size_t ws_size,
                              hipStream_t stream) {
  const float* v     = (const float*)d_in[0];
  const float* key   = (const float*)d_in[1];
  const float* query = (const float*)d_in[2];
  const int*   mask  = (const int*)d_in[3];
  const float* Wq = (const float*)d_in[4];
  const float* bq = (const float*)d_in[5];
  const float* Wk = (const float*)d_in[6];
  const float* bk = (const float*)d_in[7];
  const float* Wv = (const float*)d_in[8];
  const float* bv = (const float*)d_in[9];
  const float* Wm = (const float*)d_in[10];
  const float* bm = (const float*)d_in[11];

  float* atted = (float*)d_out;
  float* att   = atted + (size_t)ATT_OFF;

  // workspace layout (bytes): ~176 MB, unchanged
  char* ws = (char*)d_ws;
  u16* qb   = (u16*)(ws + 0);
  u16* kb   = (u16*)(ws + 33554432ll);
  u16* vvb  = (u16*)(ws + 67108864ll);
  u16* vvT  = (u16*)(ws + 100663296ll);
  u16* atp  = (u16*)(ws + 134217728ll);
  u16* WqT  = (u16*)(ws + 167772160ll);
  u16* WkT  = (u16*)(ws + 169869312ll);
  u16* WvT  = (u16*)(ws + 171966464ll);
  u16* WmT  = (u16*)(ws + 174063616ll);

  // bf16 copies of raw inputs live in the (not yet written) att region of d_out:
  // all dead before scores_softmax_pv overwrites att. Zero workspace growth.
  u16* cq = (u16*)att;
  u16* ck = cq + 16777216;
  u16* cv = ck + 16777216;

  // 0) input casts f32 -> bf16 (16M elems each, 8/thread)
  cast_bf16x8<<<8192, 256, 0, stream>>>(query, cq);
  cast_bf16x8<<<8192, 256, 0, stream>>>(key, ck);
  cast_bf16x8<<<8192, 256, 0, stream>>>(v, cv);

  // 1) weight transposes (f32 -> bf16, [k][n] -> [n][k])
  tr_w<<<dim3(32, 32), 256, 0, stream>>>(Wq, WqT);
  tr_w<<<dim3(32, 32), 256, 0, stream>>>(Wk, WkT);
  tr_w<<<dim3(32, 32), 256, 0, stream>>>(Wv, WvT);
  tr_w<<<dim3(32, 32), 256, 0, stream>>>(Wm, WmT);

  // 2) projections: [16384,1024] x [1024,1024] -> bf16 (all-bf16 gl_lds GEMM)
  gemm_bt<<<dim3(8, 128, 1), 256, 0, stream>>>(cq, WqT, bq, qb, nullptr,
                                               1024, 1024, 0, 0, 0, 0);
  gemm_bt<<<dim3(8, 128, 1), 256, 0, stream>>>(ck, WkT, bk, kb, nullptr,
                                               1024, 1024, 0, 0, 0, 0);
  gemm_bt<<<dim3(8, 128, 1), 256, 0, stream>>>(cv, WvT, bv, vvb, nullptr,
                                               1024, 1024, 0, 0, 0, 0);

  // 3) vv -> vvT[bh][d][k]
  tr_head<<<dim3(32, 4, 128), 256, 0, stream>>>(vvb, vvT);

  // 4) fused scores + mask + softmax -> att (f32) AND att@vv -> atp (bf16)
  scores_softmax_pv<<<dim3(64, 128), 256, 0, stream>>>(qb, kb, mask, vvT, att, atp);

  // 5) output projection: atp bf16 [16384,1024] x WmT -> atted f32
  gemm_bt<<<dim3(8, 128, 1), 256, 0, stream>>>(atp, WmT, bm, nullptr, atted,
                                               1024, 1024, 0, 0, 0, 0);
}

// Round 4
// 1329.223 us; speedup vs baseline: 1.1814x; 1.0060x over previous
//
#include <hip/hip_runtime.h>

typedef unsigned short u16;
typedef __attribute__((ext_vector_type(8))) short short8;   // 8 x bf16 frag (4 VGPRs)
typedef __attribute__((ext_vector_type(4))) float floatx4;  // MFMA accumulator

#define MFMA16(a, b, c) __builtin_amdgcn_mfma_f32_16x16x32_bf16(a, b, c, 0, 0, 0)

// Problem constants
#define BB 16
#define KK 1024
#define NH 1024
#define HD 8
#define DK 128
#define ATT_OFF 16777216      // atted elems (16*1024*1024) before att in d_out

typedef const __attribute__((address_space(1))) unsigned gl_u32;
typedef __attribute__((address_space(3))) unsigned lds_u32;

__device__ __forceinline__ u16 f2bf(float x) {  // RNE f32 -> bf16
  unsigned u = __builtin_bit_cast(unsigned, x);
  u += 0x7fffu + ((u >> 16) & 1u);
  return (u16)(u >> 16);
}

// async global->LDS, 16B per lane; LDS dest must be wave-uniform base (HW adds lane*16)
__device__ __forceinline__ void gload16(const u16* g, u16* l) {
  __builtin_amdgcn_global_load_lds((gl_u32*)g, (lds_u32*)l, 16, 0, 0);
}

// ---------------- input casts: f32 -> bf16, 8 elems/thread, 3 tensors in one launch --
__global__ __launch_bounds__(256) void cast3_bf16x8(
    const float* __restrict__ i0, const float* __restrict__ i1,
    const float* __restrict__ i2, u16* __restrict__ o0, u16* __restrict__ o1,
    u16* __restrict__ o2) {
  const float* in = blockIdx.y == 0 ? i0 : (blockIdx.y == 1 ? i1 : i2);
  u16* out = blockIdx.y == 0 ? o0 : (blockIdx.y == 1 ? o1 : o2);
  const size_t i = ((size_t)blockIdx.x * 256 + threadIdx.x) * 8;
  float4 f0 = *(const float4*)(in + i);
  float4 f1 = *(const float4*)(in + i + 4);
  union { u16 u[8]; uint4 v; } p;
  p.u[0] = f2bf(f0.x); p.u[1] = f2bf(f0.y); p.u[2] = f2bf(f0.z); p.u[3] = f2bf(f0.w);
  p.u[4] = f2bf(f1.x); p.u[5] = f2bf(f1.y); p.u[6] = f2bf(f1.z); p.u[7] = f2bf(f1.w);
  *(uint4*)(out + i) = p.v;
}

// ---------------- weight transpose+cast: in f32 [1024][1024] -> out bf16 [n][k] ----
__global__ __launch_bounds__(256) void tr_w(const float* __restrict__ in,
                                            u16* __restrict__ out) {
  __shared__ u16 t[32][36];
  const int tid = threadIdx.x;
  const int bx = blockIdx.x * 32;  // n base
  const int by = blockIdx.y * 32;  // k base
  const int r = tid >> 3, c4 = (tid & 7) * 4;
  float4 f = *(const float4*)(in + (size_t)(by + r) * 1024 + bx + c4);
  t[r][c4 + 0] = f2bf(f.x);
  t[r][c4 + 1] = f2bf(f.y);
  t[r][c4 + 2] = f2bf(f.z);
  t[r][c4 + 3] = f2bf(f.w);
  __syncthreads();
  union { u16 u[4]; uint2 v; } p;
#pragma unroll
  for (int i = 0; i < 4; i++) p.u[i] = t[c4 + i][r];
  *(uint2*)(out + (size_t)(bx + r) * 1024 + by + c4) = p.v;  // out[n][k] = in[k][n]
}

// ---------------- vv head transpose: vvb bf16 [b,i,h*128+d] -> vvT [bh][d][i] -------
__global__ __launch_bounds__(256) void tr_head(const u16* __restrict__ vvb,
                                               u16* __restrict__ vvT) {
  __shared__ u16 t[32][36];
  const int tid = threadIdx.x;
  const int bh = blockIdx.z, b = bh >> 3, h = bh & 7;
  const int i0 = blockIdx.x * 32, d0 = blockIdx.y * 32;
  const int r = tid >> 3, c4 = (tid & 7) * 4;
  union { u16 u[4]; uint2 v; } p;
  p.v = *(const uint2*)(vvb + (size_t)(b * KK + i0 + r) * NH + h * DK + d0 + c4);
  t[r][c4 + 0] = p.u[0];
  t[r][c4 + 1] = p.u[1];
  t[r][c4 + 2] = p.u[2];
  t[r][c4 + 3] = p.u[3];
  __syncthreads();
#pragma unroll
  for (int i = 0; i < 4; i++) p.u[i] = t[c4 + i][r];
  *(uint2*)(vvT + (size_t)(bh * DK + d0 + r) * KK + i0 + c4) = p.v;
}

// ---------------- MFMA GEMM body: C = A[M,1024-k] * Bt[N,k]^T (+bias) ---------------
// 2-phase pipeline (T3-min): double-buffered LDS, stage tile k+1 BEFORE ds_read+MFMA
// of tile k, ONE barrier per k-step (its vmcnt drain lands after ~200cy of compute).
__device__ __forceinline__ void gemm_body(
    const u16* __restrict__ Ab, const u16* __restrict__ Bb,
    const float* __restrict__ bias, u16* __restrict__ Cb, float* __restrict__ Cf,
    const int Kd, const int ldc, const int nBase, const int mBase) {
  __shared__ __align__(16) u16 As[2][128 * 32];
  __shared__ __align__(16) u16 Bs[2][128 * 32];
  const int tid = threadIdx.x;
  const int wid = tid >> 6, lane = tid & 63;
  const int wm = (wid & 1) * 64, wn = (wid >> 1) * 64;
  const int lm = lane & 15, lq = lane >> 4;
  const int rIn = lane >> 2;            // row within 16-row group
  const int sSlot = (lane & 3) * 8;     // k-offset in u16

  const u16* aS0 = Ab + (size_t)(mBase + (wid * 2 + 0) * 16 + rIn) * Kd + sSlot;
  const u16* aS1 = Ab + (size_t)(mBase + (wid * 2 + 1) * 16 + rIn) * Kd + sSlot;
  const u16* bS0 = Bb + (size_t)(nBase + (wid * 2 + 0) * 16 + rIn) * Kd + sSlot;
  const u16* bS1 = Bb + (size_t)(nBase + (wid * 2 + 1) * 16 + rIn) * Kd + sSlot;

  floatx4 acc[4][4] = {};

  // prologue: stage k0=0 into buf 0
  gload16(aS0, &As[0][(wid * 2 + 0) * 512]);
  gload16(aS1, &As[0][(wid * 2 + 1) * 512]);
  gload16(bS0, &Bs[0][(wid * 2 + 0) * 512]);
  gload16(bS1, &Bs[0][(wid * 2 + 1) * 512]);
  __syncthreads();

  int cur = 0;
  for (int k0 = 0; k0 < Kd; k0 += 32) {
    const int nxt = cur ^ 1;
    if (k0 + 32 < Kd) {   // issue next-tile stage FIRST (hides under compute)
      gload16(aS0 + k0 + 32, &As[nxt][(wid * 2 + 0) * 512]);
      gload16(aS1 + k0 + 32, &As[nxt][(wid * 2 + 1) * 512]);
      gload16(bS0 + k0 + 32, &Bs[nxt][(wid * 2 + 0) * 512]);
      gload16(bS1 + k0 + 32, &Bs[nxt][(wid * 2 + 1) * 512]);
    }
    short8 af[4], bfr[4];
#pragma unroll
    for (int t = 0; t < 4; t++) {
      af[t]  = *(const short8*)&As[cur][(wm + t * 16 + lm) * 32 + lq * 8];
      bfr[t] = *(const short8*)&Bs[cur][(wn + t * 16 + lm) * 32 + lq * 8];
    }
#pragma unroll
    for (int i = 0; i < 4; i++)
#pragma unroll
      for (int j = 0; j < 4; j++)
        acc[i][j] = MFMA16(af[i], bfr[j], acc[i][j]);
    __syncthreads();  // reads of cur done; next-tile stage drained
    cur = nxt;
  }

  // epilogue: C/D layout col=lane&15, row=(lane>>4)*4+reg
#pragma unroll
  for (int i = 0; i < 4; i++) {
    const int rowL = wm + i * 16 + lq * 4;
#pragma unroll
    for (int j = 0; j < 4; j++) {
      const int col = nBase + wn + j * 16 + lm;
      const float bval = bias ? bias[col] : 0.0f;
      const size_t base = (size_t)(mBase + rowL) * ldc + col;
#pragma unroll
      for (int r = 0; r < 4; r++) {
        const float v = acc[i][j][r] + bval;
        if (Cb) Cb[base + (size_t)r * ldc] = f2bf(v);
        if (Cf) Cf[base + (size_t)r * ldc] = v;
      }
    }
  }
}

// T1 bijective XCD swizzle for the (8,128) grid: XCD x owns mBase stripe [16x,16x+16)
__device__ __forceinline__ int2 swz_grid() {
  const int flat = blockIdx.x + 8 * blockIdx.y;   // 0..1023
  const int xcd = flat & 7, idx = flat >> 3;
  const int nflat = xcd * 128 + idx;
  return make_int2((nflat & 7) * 128, (nflat >> 3) * 128);  // (nBase, mBase)
}

__global__ __launch_bounds__(256, 2) void gemm_bt(
    const u16* __restrict__ A, const u16* __restrict__ Bt,
    const float* __restrict__ bias, u16* __restrict__ Cb, float* __restrict__ Cf) {
  int2 nm = swz_grid();
  gemm_body(A, Bt, bias, Cb, Cf, 1024, 1024, nm.x, nm.y);
}

// Q/K/V projections in ONE launch: grid (8,128,3), z selects tensor
__global__ __launch_bounds__(256, 2) void gemm_qkv(
    const u16* __restrict__ A0, const u16* __restrict__ A1,
    const u16* __restrict__ A2, const u16* __restrict__ B0,
    const u16* __restrict__ B1, const u16* __restrict__ B2,
    const float* __restrict__ b0, const float* __restrict__ b1,
    const float* __restrict__ b2, u16* __restrict__ C0, u16* __restrict__ C1,
    u16* __restrict__ C2) {
  const int z = blockIdx.z;
  const u16* A = z == 0 ? A0 : (z == 1 ? A1 : A2);
  const u16* B = z == 0 ? B0 : (z == 1 ? B1 : B2);
  const float* bias = z == 0 ? b0 : (z == 1 ? b1 : b2);
  u16* C = z == 0 ? C0 : (z == 1 ? C1 : C2);
  int2 nm = swz_grid();
  gemm_body(A, B, bias, C, nullptr, 1024, 1024, nm.x, nm.y);
}

// ---------------- fused scores + mask + softmax + PV ---------------------------------
// Block: one (b,h), 16 query rows, full 1024 keys. 4 waves x 256-col slices.
// T1 XCD swizzle keeps each bh's kb/vvT slice on one XCD's L2.
// QK and PV streams are register-double-buffered (depth 4) so each wave keeps ~16
// loads in flight — self-hiding the ~200cy L2 latency instead of paying it serially.
// LDS is EXACTLY 32768 B: p_lds doubles as mask (u16) and redM/redS scratch.
__global__ __launch_bounds__(256, 2) void scores_softmax_pv(
    const u16* __restrict__ qb, const u16* __restrict__ kb,
    const int* __restrict__ mask, const u16* __restrict__ vvT,
    float* __restrict__ att, u16* __restrict__ atp) {
  __shared__ __align__(16) u16 p_lds[16 * 1024];  // 32 KB total
  u16* msk16 = p_lds;                    // [0..1024) u16
  float* redM = (float*)&p_lds[1024];    // 64 f32
  float* redS = (float*)&p_lds[1152];    // 64 f32
  const int tid = threadIdx.x;

  // grid (64,128): flat 0..8191 round-robins XCDs; XCD x owns bh [16x,16x+16),
  // rowBlk fastest within a bh so slice reuse is temporally tight.
  const int flat = blockIdx.x + 64 * blockIdx.y;
  const int xcd = flat & 7, idx = flat >> 3;       // idx 0..1023
  const int bh = xcd * 16 + (idx >> 6);
  const int rowBlk = idx & 63;

  const int b = bh >> 3, h = bh & 7;
  const int wid = tid >> 6, lane = tid & 63;
  const int lm = lane & 15, lq = lane >> 4;
  const int rowG = rowBlk * 16;

  {
    int4 m = *(const int4*)(mask + (size_t)b * KK + tid * 4);
    msk16[tid * 4 + 0] = (u16)(m.x != 0);
    msk16[tid * 4 + 1] = (u16)(m.y != 0);
    msk16[tid * 4 + 2] = (u16)(m.z != 0);
    msk16[tid * 4 + 3] = (u16)(m.w != 0);
  }

  // q fragments: 16 rows x dk=128 (4 k-steps), held in regs
  short8 qf[4];
  const u16* qp = qb + (size_t)(b * KK + rowG + lm) * NH + h * DK + lq * 8;
#pragma unroll
  for (int ks = 0; ks < 4; ks++) qf[ks] = *(const short8*)(qp + ks * 32);

  // ---- QK^T with depth-4 register double-buffer on K fragments ----
  floatx4 acc[16] = {};
  const u16* kpB = kb + (size_t)(b * KK + wid * 256 + lm) * NH + h * DK + lq * 8;
  short8 kf[4][4];  // [slot][ks] — all indices static after full unroll
#pragma unroll
  for (int p = 0; p < 4; p++) {
    const u16* kp = kpB + (size_t)p * 16 * NH;
    kf[p][0] = *(const short8*)(kp + 0);
    kf[p][1] = *(const short8*)(kp + 32);
    kf[p][2] = *(const short8*)(kp + 64);
    kf[p][3] = *(const short8*)(kp + 96);
  }
#pragma unroll
  for (int jt = 0; jt < 16; jt++) {
    const int slot = jt & 3;
    short8 c0 = kf[slot][0], c1 = kf[slot][1], c2 = kf[slot][2], c3 = kf[slot][3];
    if (jt + 4 < 16) {  // issue refill BEFORE the MFMAs (loads fly under compute)
      const u16* kp = kpB + (size_t)(jt + 4) * 16 * NH;
      kf[slot][0] = *(const short8*)(kp + 0);
      kf[slot][1] = *(const short8*)(kp + 32);
      kf[slot][2] = *(const short8*)(kp + 64);
      kf[slot][3] = *(const short8*)(kp + 96);
    }
    floatx4 a = acc[jt];
    a = MFMA16(qf[0], c0, a);
    a = MFMA16(qf[1], c1, a);
    a = MFMA16(qf[2], c2, a);
    a = MFMA16(qf[3], c3, a);
    acc[jt] = a;
  }
  __syncthreads();  // msk stores complete

  const float scale = 0.08838834764831845f;  // 1/sqrt(128)
  float mrow[4] = {-3e38f, -3e38f, -3e38f, -3e38f};
#pragma unroll
  for (int jt = 0; jt < 16; jt++) {
    const int col = wid * 256 + jt * 16 + lm;
    const bool mk = msk16[col] != 0;
#pragma unroll
    for (int r = 0; r < 4; r++) {
      float s = mk ? -1e9f : acc[jt][r] * scale;
      acc[jt][r] = s;
      mrow[r] = fmaxf(mrow[r], s);
    }
  }
  // reduce max over the 16 lanes holding this row's cols
#pragma unroll
  for (int off = 1; off < 16; off <<= 1)
#pragma unroll
    for (int r = 0; r < 4; r++) mrow[r] = fmaxf(mrow[r], __shfl_xor(mrow[r], off));
  if (lm == 0) {
#pragma unroll
    for (int r = 0; r < 4; r++) redM[wid * 16 + lq * 4 + r] = mrow[r];
  }
  __syncthreads();
#pragma unroll
  for (int r = 0; r < 4; r++)
    mrow[r] = fmaxf(fmaxf(redM[0 + lq * 4 + r], redM[16 + lq * 4 + r]),
                    fmaxf(redM[32 + lq * 4 + r], redM[48 + lq * 4 + r]));

  float srow[4] = {0.f, 0.f, 0.f, 0.f};
#pragma unroll
  for (int jt = 0; jt < 16; jt++)
#pragma unroll
    for (int r = 0; r < 4; r++) {
      float e = __expf(acc[jt][r] - mrow[r]);
      acc[jt][r] = e;
      srow[r] += e;
    }
#pragma unroll
  for (int off = 1; off < 16; off <<= 1)
#pragma unroll
    for (int r = 0; r < 4; r++) srow[r] += __shfl_xor(srow[r], off);
  if (lm == 0) {
#pragma unroll
    for (int r = 0; r < 4; r++) redS[wid * 16 + lq * 4 + r] = srow[r];
  }
  __syncthreads();
#pragma unroll
  for (int r = 0; r < 4; r++) {
    float s = redS[0 + lq * 4 + r] + redS[16 + lq * 4 + r] +
              redS[32 + lq * 4 + r] + redS[48 + lq * 4 + r];
    srow[r] = 1.0f / s;
  }
  __syncthreads();  // alias protection: redS reads done before p_lds writes below

  // normalize; store att (f32, nontemporal, r-outer for write combining) and
  // P (bf16) to swizzled LDS: idx = (row*1024 + col) ^ ((row&7)<<3).
#pragma unroll
  for (int r = 0; r < 4; r++) {
    const int row = lq * 4 + r;
    float* attRow = att + ((size_t)bh * KK + rowG + row) * KK;
#pragma unroll
    for (int jt = 0; jt < 16; jt++) {
      const int col = wid * 256 + jt * 16 + lm;
      const float p = acc[jt][r] * srow[r];
      __builtin_nontemporal_store(p, attRow + col);
      p_lds[(row * 1024 + col) ^ ((row & 7) << 3)] = f2bf(p);
    }
  }
  __syncthreads();  // P tile complete

  // ---- PV with depth-4 register double-buffer on V streams ----
  // out tile 16 rows x 128 d; wave wid owns d-range [wid*32, wid*32+32).
  floatx4 pacc0 = {}, pacc1 = {}, pacc2 = {}, pacc3 = {};
  const u16* vBase = vvT + (size_t)bh * DK * KK + (size_t)(wid * 32 + lm) * KK + lq * 8;
  short8 vf[4][2];  // [slot][d-half]
#pragma unroll
  for (int p = 0; p < 4; p++) {
    vf[p][0] = *(const short8*)(vBase + p * 32);
    vf[p][1] = *(const short8*)(vBase + 16 * KK + p * 32);
  }
#pragma unroll
  for (int s = 0; s < 32; s++) {
    const int slot = s & 3;
    short8 v0 = vf[slot][0], v1 = vf[slot][1];
    if (s + 4 < 32) {
      vf[slot][0] = *(const short8*)(vBase + (s + 4) * 32);
      vf[slot][1] = *(const short8*)(vBase + 16 * KK + (s + 4) * 32);
    }
    short8 pf = *(const short8*)&p_lds[(lm * 1024 + s * 32 + lq * 8) ^ ((lm & 7) << 3)];
    if (s & 1) {
      pacc2 = MFMA16(pf, v0, pacc2);
      pacc3 = MFMA16(pf, v1, pacc3);
    } else {
      pacc0 = MFMA16(pf, v0, pacc0);
      pacc1 = MFMA16(pf, v1, pacc1);
    }
  }
  floatx4 o0 = pacc0 + pacc2;
  floatx4 o1 = pacc1 + pacc3;

  // epilogue: C layout col(d)=lm, row=lq*4+r; atp[b*K + row][h*128 + d] bf16
#pragma unroll
  for (int r = 0; r < 4; r++) {
    const int row = rowG + lq * 4 + r;
    atp[(size_t)(b * KK + row) * NH + h * DK + wid * 32 + 0 + lm] = f2bf(o0[r]);
    atp[(size_t)(b * KK + row) * NH + h * DK + wid * 32 + 16 + lm] = f2bf(o1[r]);
  }
}

// ---------------- launcher ----------------------------------------------------------
extern "C" void kernel_launch(void* const* d_in, const int* in_sizes, int n_in,
                              void* d_out, int out_size, void* d_ws, size_t ws_size,
                              hipStream_t stream) {
  const float* v     = (const float*)d_in[0];
  const float* key   = (const float*)d_in[1];
  const float* query = (const float*)d_in[2];
  const int*   mask  = (const int*)d_in[3];
  const float* Wq = (const float*)d_in[4];
  const float* bq = (const float*)d_in[5];
  const float* Wk = (const float*)d_in[6];
  const float* bk = (const float*)d_in[7];
  const float* Wv = (const float*)d_in[8];
  const float* bv = (const float*)d_in[9];
  const float* Wm = (const float*)d_in[10];
  const float* bm = (const float*)d_in[11];

  float* atted = (float*)d_out;
  float* att   = atted + (size_t)ATT_OFF;

  // workspace layout (bytes): ~176 MB, unchanged
  char* ws = (char*)d_ws;
  u16* qb   = (u16*)(ws + 0);
  u16* kb   = (u16*)(ws + 33554432ll);
  u16* vvb  = (u16*)(ws + 67108864ll);
  u16* vvT  = (u16*)(ws + 100663296ll);
  u16* atp  = (u16*)(ws + 134217728ll);
  u16* WqT  = (u16*)(ws + 167772160ll);
  u16* WkT  = (u16*)(ws + 169869312ll);
  u16* WvT  = (u16*)(ws + 171966464ll);
  u16* WmT  = (u16*)(ws + 174063616ll);

  // bf16 copies of raw inputs live in the (not yet written) att region of d_out:
  // all dead before scores_softmax_pv overwrites att. Zero workspace growth.
  u16* cq = (u16*)att;
  u16* ck = cq + 16777216;
  u16* cv = ck + 16777216;

  // 0) input casts f32 -> bf16 (16M elems each, 8/thread), one launch
  cast3_bf16x8<<<dim3(8192, 3), 256, 0, stream>>>(query, key, v, cq, ck, cv);

  // 1) weight transposes (f32 -> bf16, [k][n] -> [n][k])
  tr_w<<<dim3(32, 32), 256, 0, stream>>>(Wq, WqT);
  tr_w<<<dim3(32, 32), 256, 0, stream>>>(Wk, WkT);
  tr_w<<<dim3(32, 32), 256, 0, stream>>>(Wv, WvT);
  tr_w<<<dim3(32, 32), 256, 0, stream>>>(Wm, WmT);

  // 2) Q/K/V projections in one launch: [16384,1024] x [1024,1024] -> bf16
  gemm_qkv<<<dim3(8, 128, 3), 256, 0, stream>>>(cq, ck, cv, WqT, WkT, WvT,
                                                bq, bk, bv, qb, kb, vvb);

  // 3) vv -> vvT[bh][d][k]
  tr_head<<<dim3(32, 4, 128), 256, 0, stream>>>(vvb, vvT);

  // 4) fused scores + mask + softmax -> att (f32) AND att@vv -> atp (bf16)
  scores_softmax_pv<<<dim3(64, 128), 256, 0, stream>>>(qb, kb, mask, vvT, att, atp);

  // 5) output projection: atp bf16 [16384,1024] x WmT -> atted f32
  gemm_bt<<<dim3(8, 128), 256, 0, stream>>>(atp, WmT, bm, nullptr, atted);
}

// Round 5
// 1122.392 us; speedup vs baseline: 1.3991x; 1.1843x over previous
//
#include <hip/hip_runtime.h>

typedef unsigned short u16;
typedef __attribute__((ext_vector_type(8))) short short8;   // 8 x bf16 frag (4 VGPRs)
typedef __attribute__((ext_vector_type(4))) float floatx4;  // MFMA accumulator

#define MFMA16(a, b, c) __builtin_amdgcn_mfma_f32_16x16x32_bf16(a, b, c, 0, 0, 0)

// Problem constants
#define BB 16
#define KK 1024
#define NH 1024
#define HD 8
#define DK 128
#define ATT_OFF 16777216      // atted elems (16*1024*1024) before att in d_out

typedef const __attribute__((address_space(1))) unsigned gl_u32;
typedef __attribute__((address_space(3))) unsigned lds_u32;

__device__ __forceinline__ u16 f2bf(float x) {  // RNE f32 -> bf16
  unsigned u = __builtin_bit_cast(unsigned, x);
  u += 0x7fffu + ((u >> 16) & 1u);
  return (u16)(u >> 16);
}

// async global->LDS, 16B per lane; LDS dest must be wave-uniform base (HW adds lane*16)
__device__ __forceinline__ void gload16(const u16* g, u16* l) {
  __builtin_amdgcn_global_load_lds((gl_u32*)g, (lds_u32*)l, 16, 0, 0);
}

// ---------------- input casts: f32 -> bf16, 8 elems/thread, 3 tensors in one launch --
__global__ __launch_bounds__(256) void cast3_bf16x8(
    const float* __restrict__ i0, const float* __restrict__ i1,
    const float* __restrict__ i2, u16* __restrict__ o0, u16* __restrict__ o1,
    u16* __restrict__ o2) {
  const float* in = blockIdx.y == 0 ? i0 : (blockIdx.y == 1 ? i1 : i2);
  u16* out = blockIdx.y == 0 ? o0 : (blockIdx.y == 1 ? o1 : o2);
  const size_t i = ((size_t)blockIdx.x * 256 + threadIdx.x) * 8;
  float4 f0 = *(const float4*)(in + i);
  float4 f1 = *(const float4*)(in + i + 4);
  union { u16 u[8]; uint4 v; } p;
  p.u[0] = f2bf(f0.x); p.u[1] = f2bf(f0.y); p.u[2] = f2bf(f0.z); p.u[3] = f2bf(f0.w);
  p.u[4] = f2bf(f1.x); p.u[5] = f2bf(f1.y); p.u[6] = f2bf(f1.z); p.u[7] = f2bf(f1.w);
  *(uint4*)(out + i) = p.v;
}

// ---------------- weight transpose+cast: 4 weights in one launch (z selects) --------
__global__ __launch_bounds__(256) void tr_w4(
    const float* __restrict__ w0, const float* __restrict__ w1,
    const float* __restrict__ w2, const float* __restrict__ w3,
    u16* __restrict__ o0, u16* __restrict__ o1, u16* __restrict__ o2,
    u16* __restrict__ o3) {
  const int z = blockIdx.z;
  const float* in = z == 0 ? w0 : (z == 1 ? w1 : (z == 2 ? w2 : w3));
  u16* out = z == 0 ? o0 : (z == 1 ? o1 : (z == 2 ? o2 : o3));
  __shared__ u16 t[32][36];
  const int tid = threadIdx.x;
  const int bx = blockIdx.x * 32;  // n base
  const int by = blockIdx.y * 32;  // k base
  const int r = tid >> 3, c4 = (tid & 7) * 4;
  float4 f = *(const float4*)(in + (size_t)(by + r) * 1024 + bx + c4);
  t[r][c4 + 0] = f2bf(f.x);
  t[r][c4 + 1] = f2bf(f.y);
  t[r][c4 + 2] = f2bf(f.z);
  t[r][c4 + 3] = f2bf(f.w);
  __syncthreads();
  union { u16 u[4]; uint2 v; } p;
#pragma unroll
  for (int i = 0; i < 4; i++) p.u[i] = t[c4 + i][r];
  *(uint2*)(out + (size_t)(bx + r) * 1024 + by + c4) = p.v;  // out[n][k] = in[k][n]
}

// ---------------- vv head transpose: vvb bf16 [b,i,h*128+d] -> vvT [bh][d][i] -------
__global__ __launch_bounds__(256) void tr_head(const u16* __restrict__ vvb,
                                               u16* __restrict__ vvT) {
  __shared__ u16 t[32][36];
  const int tid = threadIdx.x;
  const int bh = blockIdx.z, b = bh >> 3, h = bh & 7;
  const int i0 = blockIdx.x * 32, d0 = blockIdx.y * 32;
  const int r = tid >> 3, c4 = (tid & 7) * 4;
  union { u16 u[4]; uint2 v; } p;
  p.v = *(const uint2*)(vvb + (size_t)(b * KK + i0 + r) * NH + h * DK + d0 + c4);
  t[r][c4 + 0] = p.u[0];
  t[r][c4 + 1] = p.u[1];
  t[r][c4 + 2] = p.u[2];
  t[r][c4 + 3] = p.u[3];
  __syncthreads();
#pragma unroll
  for (int i = 0; i < 4; i++) p.u[i] = t[c4 + i][r];
  *(uint2*)(vvT + (size_t)(bh * DK + d0 + r) * KK + i0 + c4) = p.v;
}

// ---------------- MFMA GEMM body: C = A[M,1024-k] * Bt[N,k]^T (+bias) ---------------
// 2-phase pipeline (T3-min): double-buffered LDS, stage tile k+1 BEFORE ds_read+MFMA
// of tile k, ONE barrier per k-step.
__device__ __forceinline__ void gemm_body(
    const u16* __restrict__ Ab, const u16* __restrict__ Bb,
    const float* __restrict__ bias, u16* __restrict__ Cb, float* __restrict__ Cf,
    const int Kd, const int ldc, const int nBase, const int mBase) {
  __shared__ __align__(16) u16 As[2][128 * 32];
  __shared__ __align__(16) u16 Bs[2][128 * 32];
  const int tid = threadIdx.x;
  const int wid = tid >> 6, lane = tid & 63;
  const int wm = (wid & 1) * 64, wn = (wid >> 1) * 64;
  const int lm = lane & 15, lq = lane >> 4;
  const int rIn = lane >> 2;            // row within 16-row group
  const int sSlot = (lane & 3) * 8;     // k-offset in u16

  const u16* aS0 = Ab + (size_t)(mBase + (wid * 2 + 0) * 16 + rIn) * Kd + sSlot;
  const u16* aS1 = Ab + (size_t)(mBase + (wid * 2 + 1) * 16 + rIn) * Kd + sSlot;
  const u16* bS0 = Bb + (size_t)(nBase + (wid * 2 + 0) * 16 + rIn) * Kd + sSlot;
  const u16* bS1 = Bb + (size_t)(nBase + (wid * 2 + 1) * 16 + rIn) * Kd + sSlot;

  floatx4 acc[4][4] = {};

  // prologue: stage k0=0 into buf 0
  gload16(aS0, &As[0][(wid * 2 + 0) * 512]);
  gload16(aS1, &As[0][(wid * 2 + 1) * 512]);
  gload16(bS0, &Bs[0][(wid * 2 + 0) * 512]);
  gload16(bS1, &Bs[0][(wid * 2 + 1) * 512]);
  __syncthreads();

  int cur = 0;
  for (int k0 = 0; k0 < Kd; k0 += 32) {
    const int nxt = cur ^ 1;
    if (k0 + 32 < Kd) {   // issue next-tile stage FIRST (hides under compute)
      gload16(aS0 + k0 + 32, &As[nxt][(wid * 2 + 0) * 512]);
      gload16(aS1 + k0 + 32, &As[nxt][(wid * 2 + 1) * 512]);
      gload16(bS0 + k0 + 32, &Bs[nxt][(wid * 2 + 0) * 512]);
      gload16(bS1 + k0 + 32, &Bs[nxt][(wid * 2 + 1) * 512]);
    }
    short8 af[4], bfr[4];
#pragma unroll
    for (int t = 0; t < 4; t++) {
      af[t]  = *(const short8*)&As[cur][(wm + t * 16 + lm) * 32 + lq * 8];
      bfr[t] = *(const short8*)&Bs[cur][(wn + t * 16 + lm) * 32 + lq * 8];
    }
#pragma unroll
    for (int i = 0; i < 4; i++)
#pragma unroll
      for (int j = 0; j < 4; j++)
        acc[i][j] = MFMA16(af[i], bfr[j], acc[i][j]);
    __syncthreads();  // reads of cur done; next-tile stage drained
    cur = nxt;
  }

  // epilogue: C/D layout col=lane&15, row=(lane>>4)*4+reg
#pragma unroll
  for (int i = 0; i < 4; i++) {
    const int rowL = wm + i * 16 + lq * 4;
#pragma unroll
    for (int j = 0; j < 4; j++) {
      const int col = nBase + wn + j * 16 + lm;
      const float bval = bias ? bias[col] : 0.0f;
      const size_t base = (size_t)(mBase + rowL) * ldc + col;
#pragma unroll
      for (int r = 0; r < 4; r++) {
        const float v = acc[i][j][r] + bval;
        if (Cb) Cb[base + (size_t)r * ldc] = f2bf(v);
        if (Cf) Cf[base + (size_t)r * ldc] = v;
      }
    }
  }
}

// T1 bijective XCD swizzle for the (8,128) grid: XCD x owns mBase stripe [16x,16x+16)
__device__ __forceinline__ int2 swz_grid() {
  const int flat = blockIdx.x + 8 * blockIdx.y;   // 0..1023
  const int xcd = flat & 7, idx = flat >> 3;
  const int nflat = xcd * 128 + idx;
  return make_int2((nflat & 7) * 128, (nflat >> 3) * 128);  // (nBase, mBase)
}

__global__ __launch_bounds__(256, 2) void gemm_bt(
    const u16* __restrict__ A, const u16* __restrict__ Bt,
    const float* __restrict__ bias, u16* __restrict__ Cb, float* __restrict__ Cf) {
  int2 nm = swz_grid();
  gemm_body(A, Bt, bias, Cb, Cf, 1024, 1024, nm.x, nm.y);
}

// Q/K/V projections in ONE launch: grid (8,128,3), z selects tensor
__global__ __launch_bounds__(256, 2) void gemm_qkv(
    const u16* __restrict__ A0, const u16* __restrict__ A1,
    const u16* __restrict__ A2, const u16* __restrict__ B0,
    const u16* __restrict__ B1, const u16* __restrict__ B2,
    const float* __restrict__ b0, const float* __restrict__ b1,
    const float* __restrict__ b2, u16* __restrict__ C0, u16* __restrict__ C1,
    u16* __restrict__ C2) {
  const int z = blockIdx.z;
  const u16* A = z == 0 ? A0 : (z == 1 ? A1 : A2);
  const u16* B = z == 0 ? B0 : (z == 1 ? B1 : B2);
  const float* bias = z == 0 ? b0 : (z == 1 ? b1 : b2);
  u16* C = z == 0 ? C0 : (z == 1 ? C1 : C2);
  int2 nm = swz_grid();
  gemm_body(A, B, bias, C, nullptr, 1024, 1024, nm.x, nm.y);
}

// ---------------- fused scores + mask + softmax + PV ---------------------------------
// Block: one (b,h), 32 query rows (2 row-groups), full 1024 keys. 4 waves x 256 cols.
// Doubling rows per block doubles MFMA work per K/V load (the latency-bound fix) and
// halves total L2 K/V traffic. acc[2][16] lives in AGPRs (unified file).
// att global stores moved to kernel END: no __syncthreads (vmcnt(0) drain) after them.
// LDS = exactly 64 KB (P tile 32x1024 bf16); mask/redM/redS alias its first rows
// (dead before P writes; barrier after final redS read protects the alias).
__global__ __launch_bounds__(256, 2) void scores_softmax_pv(
    const u16* __restrict__ qb, const u16* __restrict__ kb,
    const int* __restrict__ mask, const u16* __restrict__ vvT,
    float* __restrict__ att, u16* __restrict__ atp) {
  __shared__ __align__(16) u16 p_lds[32 * 1024];  // 64 KB total
  u16* msk16 = p_lds;                    // [0..1024) u16
  float* redM = (float*)&p_lds[1024];    // 128 f32  [1024..1280)
  float* redS = (float*)&p_lds[1280];    // 128 f32  [1280..1536)
  const int tid = threadIdx.x;

  // grid (32,128): flat 0..4095 round-robins XCDs; XCD x owns bh [16x,16x+16),
  // rowBlk fastest within a bh so kb/vvT slice reuse is temporally tight (L2-hot).
  const int flat = blockIdx.x + 32 * blockIdx.y;
  const int xcd = flat & 7, idx = flat >> 3;       // idx 0..511
  const int bh = xcd * 16 + (idx >> 5);
  const int rowBlk = idx & 31;

  const int b = bh >> 3, h = bh & 7;
  const int wid = tid >> 6, lane = tid & 63;
  const int lm = lane & 15, lq = lane >> 4;
  const int rowG = rowBlk * 32;

  {
    int4 m = *(const int4*)(mask + (size_t)b * KK + tid * 4);
    msk16[tid * 4 + 0] = (u16)(m.x != 0);
    msk16[tid * 4 + 1] = (u16)(m.y != 0);
    msk16[tid * 4 + 2] = (u16)(m.z != 0);
    msk16[tid * 4 + 3] = (u16)(m.w != 0);
  }

  // q fragments: 2 row-groups x 16 rows x dk=128 (4 k-steps), in regs
  short8 qf[2][4];
#pragma unroll
  for (int g = 0; g < 2; g++) {
    const u16* qp = qb + (size_t)(b * KK + rowG + g * 16 + lm) * NH + h * DK + lq * 8;
#pragma unroll
    for (int ks = 0; ks < 4; ks++) qf[g][ks] = *(const short8*)(qp + ks * 32);
  }

  // ---- QK^T: each K-frag load feeds 2 MFMAs (one per row-group) ----
  floatx4 acc[2][16] = {};
  const u16* kpB = kb + (size_t)(b * KK + wid * 256 + lm) * NH + h * DK + lq * 8;
#pragma unroll
  for (int jt = 0; jt < 16; jt++) {
    const u16* kp = kpB + (size_t)jt * 16 * NH;
    short8 k0 = *(const short8*)(kp + 0);
    short8 k1 = *(const short8*)(kp + 32);
    short8 k2 = *(const short8*)(kp + 64);
    short8 k3 = *(const short8*)(kp + 96);
    floatx4 a0 = acc[0][jt], a1 = acc[1][jt];
    a0 = MFMA16(qf[0][0], k0, a0);
    a1 = MFMA16(qf[1][0], k0, a1);
    a0 = MFMA16(qf[0][1], k1, a0);
    a1 = MFMA16(qf[1][1], k1, a1);
    a0 = MFMA16(qf[0][2], k2, a0);
    a1 = MFMA16(qf[1][2], k2, a1);
    a0 = MFMA16(qf[0][3], k3, a0);
    a1 = MFMA16(qf[1][3], k3, a1);
    acc[0][jt] = a0;
    acc[1][jt] = a1;
  }
  __syncthreads();  // msk stores complete

  const float scale = 0.08838834764831845f;  // 1/sqrt(128)
  float mrow[2][4];
#pragma unroll
  for (int g = 0; g < 2; g++)
#pragma unroll
    for (int r = 0; r < 4; r++) mrow[g][r] = -3e38f;
#pragma unroll
  for (int jt = 0; jt < 16; jt++) {
    const int col = wid * 256 + jt * 16 + lm;
    const bool mk = msk16[col] != 0;
#pragma unroll
    for (int g = 0; g < 2; g++)
#pragma unroll
      for (int r = 0; r < 4; r++) {
        float s = mk ? -1e9f : acc[g][jt][r] * scale;
        acc[g][jt][r] = s;
        mrow[g][r] = fmaxf(mrow[g][r], s);
      }
  }
  // reduce max over the 16 lanes holding this row's cols
#pragma unroll
  for (int off = 1; off < 16; off <<= 1)
#pragma unroll
    for (int g = 0; g < 2; g++)
#pragma unroll
      for (int r = 0; r < 4; r++)
        mrow[g][r] = fmaxf(mrow[g][r], __shfl_xor(mrow[g][r], off));
  if (lm == 0) {
#pragma unroll
    for (int g = 0; g < 2; g++)
#pragma unroll
      for (int r = 0; r < 4; r++)
        redM[wid * 32 + g * 16 + lq * 4 + r] = mrow[g][r];
  }
  __syncthreads();
#pragma unroll
  for (int g = 0; g < 2; g++)
#pragma unroll
    for (int r = 0; r < 4; r++) {
      const int e = g * 16 + lq * 4 + r;
      mrow[g][r] = fmaxf(fmaxf(redM[0 + e], redM[32 + e]),
                         fmaxf(redM[64 + e], redM[96 + e]));
    }

  float srow[2][4] = {};
#pragma unroll
  for (int jt = 0; jt < 16; jt++)
#pragma unroll
    for (int g = 0; g < 2; g++)
#pragma unroll
      for (int r = 0; r < 4; r++) {
        float e = __expf(acc[g][jt][r] - mrow[g][r]);
        acc[g][jt][r] = e;
        srow[g][r] += e;
      }
#pragma unroll
  for (int off = 1; off < 16; off <<= 1)
#pragma unroll
    for (int g = 0; g < 2; g++)
#pragma unroll
      for (int r = 0; r < 4; r++) srow[g][r] += __shfl_xor(srow[g][r], off);
  if (lm == 0) {
#pragma unroll
    for (int g = 0; g < 2; g++)
#pragma unroll
      for (int r = 0; r < 4; r++)
        redS[wid * 32 + g * 16 + lq * 4 + r] = srow[g][r];
  }
  __syncthreads();
#pragma unroll
  for (int g = 0; g < 2; g++)
#pragma unroll
    for (int r = 0; r < 4; r++) {
      const int e = g * 16 + lq * 4 + r;
      srow[g][r] = 1.0f / (redS[0 + e] + redS[32 + e] + redS[64 + e] + redS[96 + e]);
    }
  __syncthreads();  // alias protection: redS reads done before p_lds writes below

  // normalize in-place (acc keeps p for the end-of-kernel att stores) and write
  // the bf16 P tile to swizzled LDS: idx = (row*1024 + col) ^ ((row&7)<<3).
#pragma unroll
  for (int g = 0; g < 2; g++)
#pragma unroll
    for (int r = 0; r < 4; r++) {
      const int row = g * 16 + lq * 4 + r;
#pragma unroll
      for (int jt = 0; jt < 16; jt++) {
        const int col = wid * 256 + jt * 16 + lm;
        const float p = acc[g][jt][r] * srow[g][r];
        acc[g][jt][r] = p;
        p_lds[(row * 1024 + col) ^ ((row & 7) << 3)] = f2bf(p);
      }
    }
  __syncthreads();  // P tile complete (LDS-only drain; no global stores pending)

  // ---- PV: out 32 rows x 128 d; wave wid owns d-range [wid*32, wid*32+32).
  // Each V load feeds 2 MFMAs (one per row-group); 4 independent acc chains.
  floatx4 pacc[2][2] = {};
  const u16* vBase = vvT + (size_t)bh * DK * KK + (size_t)(wid * 32 + lm) * KK + lq * 8;
#pragma unroll 8
  for (int s = 0; s < 32; s++) {
    short8 v0 = *(const short8*)(vBase + s * 32);
    short8 v1 = *(const short8*)(vBase + 16 * KK + s * 32);
    short8 pf0 = *(const short8*)&p_lds[((0 + lm) * 1024 + s * 32 + lq * 8) ^ ((lm & 7) << 3)];
    short8 pf1 = *(const short8*)&p_lds[((16 + lm) * 1024 + s * 32 + lq * 8) ^ ((lm & 7) << 3)];
    pacc[0][0] = MFMA16(pf0, v0, pacc[0][0]);
    pacc[0][1] = MFMA16(pf0, v1, pacc[0][1]);
    pacc[1][0] = MFMA16(pf1, v0, pacc[1][0]);
    pacc[1][1] = MFMA16(pf1, v1, pacc[1][1]);
  }

  // atp epilogue: C layout col(d)=lm, row=lq*4+r
#pragma unroll
  for (int g = 0; g < 2; g++)
#pragma unroll
    for (int r = 0; r < 4; r++) {
      const int row = rowG + g * 16 + lq * 4 + r;
      atp[(size_t)(b * KK + row) * NH + h * DK + wid * 32 + 0 + lm] = f2bf(pacc[g][0][r]);
      atp[(size_t)(b * KK + row) * NH + h * DK + wid * 32 + 16 + lm] = f2bf(pacc[g][1][r]);
    }

  // att stores LAST (nontemporal, write-once output): no barrier follows, so the
  // store drain overlaps the dispatch tail instead of serializing mid-kernel.
#pragma unroll
  for (int g = 0; g < 2; g++)
#pragma unroll
    for (int r = 0; r < 4; r++) {
      const int row = g * 16 + lq * 4 + r;
      float* attRow = att + ((size_t)bh * KK + rowG + row) * KK;
#pragma unroll
      for (int jt = 0; jt < 16; jt++) {
        const int col = wid * 256 + jt * 16 + lm;
        __builtin_nontemporal_store(acc[g][jt][r], attRow + col);
      }
    }
}

// ---------------- launcher ----------------------------------------------------------
extern "C" void kernel_launch(void* const* d_in, const int* in_sizes, int n_in,
                              void* d_out, int out_size, void* d_ws, size_t ws_size,
                              hipStream_t stream) {
  const float* v     = (const float*)d_in[0];
  const float* key   = (const float*)d_in[1];
  const float* query = (const float*)d_in[2];
  const int*   mask  = (const int*)d_in[3];
  const float* Wq = (const float*)d_in[4];
  const float* bq = (const float*)d_in[5];
  const float* Wk = (const float*)d_in[6];
  const float* bk = (const float*)d_in[7];
  const float* Wv = (const float*)d_in[8];
  const float* bv = (const float*)d_in[9];
  const float* Wm = (const float*)d_in[10];
  const float* bm = (const float*)d_in[11];

  float* atted = (float*)d_out;
  float* att   = atted + (size_t)ATT_OFF;

  // workspace layout (bytes): ~176 MB, unchanged
  char* ws = (char*)d_ws;
  u16* qb   = (u16*)(ws + 0);
  u16* kb   = (u16*)(ws + 33554432ll);
  u16* vvb  = (u16*)(ws + 67108864ll);
  u16* vvT  = (u16*)(ws + 100663296ll);
  u16* atp  = (u16*)(ws + 134217728ll);
  u16* WqT  = (u16*)(ws + 167772160ll);
  u16* WkT  = (u16*)(ws + 169869312ll);
  u16* WvT  = (u16*)(ws + 171966464ll);
  u16* WmT  = (u16*)(ws + 174063616ll);

  // bf16 copies of raw inputs live in the (not yet written) att region of d_out:
  // all dead before scores_softmax_pv overwrites att. Zero workspace growth.
  u16* cq = (u16*)att;
  u16* ck = cq + 16777216;
  u16* cv = ck + 16777216;

  // 0) input casts f32 -> bf16 (16M elems each, 8/thread), one launch
  cast3_bf16x8<<<dim3(8192, 3), 256, 0, stream>>>(query, key, v, cq, ck, cv);

  // 1) weight transposes (f32 -> bf16, [k][n] -> [n][k]), one launch
  tr_w4<<<dim3(32, 32, 4), 256, 0, stream>>>(Wq, Wk, Wv, Wm, WqT, WkT, WvT, WmT);

  // 2) Q/K/V projections in one launch: [16384,1024] x [1024,1024] -> bf16
  gemm_qkv<<<dim3(8, 128, 3), 256, 0, stream>>>(cq, ck, cv, WqT, WkT, WvT,
                                                bq, bk, bv, qb, kb, vvb);

  // 3) vv -> vvT[bh][d][k]
  tr_head<<<dim3(32, 4, 128), 256, 0, stream>>>(vvb, vvT);

  // 4) fused scores + mask + softmax -> att (f32) AND att@vv -> atp (bf16)
  scores_softmax_pv<<<dim3(32, 128), 256, 0, stream>>>(qb, kb, mask, vvT, att, atp);

  // 5) output projection: atp bf16 [16384,1024] x WmT -> atted f32
  gemm_bt<<<dim3(8, 128), 256, 0, stream>>>(atp, WmT, bm, nullptr, atted);
}